// Round 12
// baseline (109.571 us; speedup 1.0000x reference)
//
#include <hip/hip_runtime.h>
#include <math.h>

constexpr int B = 2;
constexpr int S = 2048;
constexpr int DMODEL = 1024;
constexpr int H = 16;
constexpr int M_TOT = B * S;                     // 4096
constexpr size_t MAT = (size_t)B * S * DMODEL;   // 4,194,304 elements

typedef __attribute__((ext_vector_type(8))) __bf16 bf16x8;
typedef __attribute__((ext_vector_type(4))) float f32x4;

#define GLOAD16(g, l) __builtin_amdgcn_global_load_lds( \
    (const __attribute__((address_space(1))) void*)(g), \
    (__attribute__((address_space(3))) void*)(l), 16, 0, 0)

__device__ __forceinline__ float bf2f(__bf16 v) { return (float)v; }
__device__ __forceinline__ __bf16 f2bf(float v) { return (__bf16)v; }
__device__ __forceinline__ float silu(float z) { return z / (1.0f + expf(-z)); }

// ---------------------------------------------------------------------------
// Merged prep: [0,2048) x fp32->bf16 ; [2048,7168) W transpose+convert ;
// [7168,7184) bias pack ; [7184,7312) rotary cs tables ; [7312,7320) decay
// tables. Tables use full-precision libm (computed once, 264 KB total).
// ---------------------------------------------------------------------------
__global__ __launch_bounds__(256) void prep_kernel(
    const float* __restrict__ x, __bf16* __restrict__ xb,
    const float* Wq, const float* Wk, const float* Wv, const float* Wg,
    const float* Wo, __bf16* __restrict__ wqkvg_t, __bf16* __restrict__ wo_t,
    const float* bq, const float* bk, const float* bv, const float* bg,
    float* __restrict__ bqkvg,
    float2* __restrict__ csq, float2* __restrict__ csk,
    float* __restrict__ wdec)
{
    __shared__ float tile[32][33];
    const int bid = blockIdx.x;
    const int tid = threadIdx.x;

    if (bid < 2048) {
        const size_t p = (size_t)bid * 256 + tid;
        const float4 a = reinterpret_cast<const float4*>(x)[2 * p];
        const float4 b = reinterpret_cast<const float4*>(x)[2 * p + 1];
        bf16x8 o;
        o[0] = f2bf(a.x); o[1] = f2bf(a.y); o[2] = f2bf(a.z); o[3] = f2bf(a.w);
        o[4] = f2bf(b.x); o[5] = f2bf(b.y); o[6] = f2bf(b.z); o[7] = f2bf(b.w);
        reinterpret_cast<bf16x8*>(xb)[p] = o;
    } else if (bid < 7168) {
        const int idx = bid - 2048;
        const int z = idx >> 10;
        const int rem = idx & 1023;
        const int n0 = (rem & 31) * 32, k0 = (rem >> 5) * 32;
        const float* W = (z == 0) ? Wq : (z == 1) ? Wk : (z == 2) ? Wv
                        : (z == 3) ? Wg : Wo;
        const int tx = tid & 31, ty = tid >> 5;
        #pragma unroll
        for (int i = 0; i < 32; i += 8)
            tile[ty + i][tx] = W[(size_t)(k0 + ty + i) * DMODEL + n0 + tx];
        __syncthreads();
        #pragma unroll
        for (int i = 0; i < 32; i += 8) {
            const int n = n0 + ty + i, kk = k0 + tx;
            const __bf16 val = f2bf(tile[tx][ty + i]);
            if (z < 4) wqkvg_t[((size_t)z * 1024 + n) * DMODEL + kk] = val;
            else       wo_t[(size_t)n * DMODEL + kk] = val;
        }
    } else if (bid < 7184) {
        const int i = (bid - 7168) * 256 + tid;
        const float* src = ((i >> 10) == 0) ? bq : ((i >> 10) == 1) ? bk
                          : ((i >> 10) == 2) ? bv : bg;
        bqkvg[i] = src[i & 1023];
    } else if (bid < 7312) {
        // rotary cs tables: e = s*16 + j, 32768 entries
        const int e = (bid - 7184) * 256 + tid;
        const int s = e >> 4, j = e & 15;
        const float inv_freq = powf(10000.0f, -(float)j / 16.0f);
        const float freq = (float)s * inv_freq;
        const float c = cosf(freq), sn = sinf(freq);
        const float base = (2.0f * (float)j + 12.8f) / 44.8f;
        const float sc = powf(base, ((float)s - 1024.0f) / 512.0f);
        csq[e] = make_float2(c * sc, sn * sc);
        csk[e] = make_float2(c / sc, sn / sc);
    } else {
        // decay tables: [0,1024) q: gamma^(sloc+1); [1024,2048) k: gamma^(63-sloc)
        const int e = (bid - 7312) * 256 + tid;
        const int which = e >> 10;
        const int idx = e & 1023;
        const int h = idx >> 6, sl = idx & 63;
        const float gamma = 1.0f - exp2f(-5.0f - (float)h);
        const float l2g = log2f(gamma);
        wdec[e] = (which == 0) ? exp2f((float)(sl + 1) * l2g)
                               : exp2f((float)(63 - sl) * l2g);
    }
}

// ---------------------------------------------------------------------------
// Swizzled LDS layout for 64B (BK=32 bf16) rows.
// Physical slot = logical slot ^ ((row>>1)&3)  -> 2 lanes/bank (free).
// ---------------------------------------------------------------------------
__device__ __forceinline__ bf16x8 ldsfrag(const char* base, int row, int kbyte)
{
    return *(const bf16x8*)(base + row * 64 + (kbyte ^ (((row >> 1) & 3) << 4)));
}

// ---------------------------------------------------------------------------
// QKVG GEMM: 256x128 tile, 512 thr, ring-2 LDS 48KB, 2 blocks/CU, counted
// vmcnt(3). Epilogue fuses xPos rotary + decay fold for q/k via PRECOMPUTED
// TABLES (zero transcendentals — R11's fast-math version still burned ~16us
// in the trans pipe).
// ---------------------------------------------------------------------------
__global__ __launch_bounds__(512, 4) void gemm_qkvg(
    const __bf16* __restrict__ A, const __bf16* __restrict__ Bt,
    const float* __restrict__ bias,
    __bf16* o0, __bf16* o1, __bf16* o2, __bf16* o3,
    const float2* __restrict__ csq, const float2* __restrict__ csk,
    const float* __restrict__ wdec)
{
    __shared__ char lds[49152];     // A 2x16KB @0, B 2x8KB @32768
    constexpr int NTK = 32;         // 1024 / 32

    const int tid = threadIdx.x, wv = tid >> 6, ln = tid & 63;
    const int wm = wv >> 1, wn = wv & 1;

    // bijective XCD swizzle (nwg=512, cpx=64)
    int bid = blockIdx.x;
    bid = (bid & 7) * 64 + (bid >> 3);
    const int bx = bid & 31, by = bid >> 5;
    const int row0 = by * 256, col0 = bx * 128;

    const int lrow = ln & 15;
    const int kb   = (ln >> 4) * 16;

    f32x4 acc[4][4] = {};

    auto stageA = [&](int k0, char* buf) {
        #pragma unroll
        for (int j = 0; j < 2; ++j) {
            const int r  = j * 128 + (tid >> 2);
            const int cb = ((tid & 3) * 16) ^ (((r >> 1) & 3) << 4);
            GLOAD16((const char*)(A + ((size_t)(row0 + r) << 10) + k0) + cb,
                    buf + j * 8192 + wv * 1024);
        }
    };
    auto stageB = [&](int k0, char* buf) {
        const int r  = tid >> 2;
        const int cb = ((tid & 3) * 16) ^ (((r >> 1) & 3) << 4);
        GLOAD16((const char*)(Bt + ((size_t)(col0 + r) << 10) + k0) + cb,
                buf + wv * 1024);
    };

    stageA(0, lds);
    stageB(0, lds + 32768);

    for (int t = 0; t < NTK; ++t) {
        char* ab = lds + (t & 1) * 16384;
        char* bb = lds + 32768 + (t & 1) * 8192;

        if (t + 1 < NTK) {
            stageA((t + 1) * 32, lds + ((t + 1) & 1) * 16384);
            stageB((t + 1) * 32, lds + 32768 + ((t + 1) & 1) * 8192);
            asm volatile("s_waitcnt vmcnt(3)" ::: "memory");
        } else {
            asm volatile("s_waitcnt vmcnt(0)" ::: "memory");
        }
        __builtin_amdgcn_s_barrier();
        __builtin_amdgcn_sched_barrier(0);

        bf16x8 af[4], bf[4];
        #pragma unroll
        for (int mf = 0; mf < 4; ++mf)
            af[mf] = ldsfrag(ab, wm * 64 + mf * 16 + lrow, kb);
        #pragma unroll
        for (int nf = 0; nf < 4; ++nf)
            bf[nf] = ldsfrag(bb, wn * 64 + nf * 16 + lrow, kb);

        __builtin_amdgcn_s_setprio(1);
        #pragma unroll
        for (int mf = 0; mf < 4; ++mf)
            #pragma unroll
            for (int nf = 0; nf < 4; ++nf)
                acc[mf][nf] = __builtin_amdgcn_mfma_f32_16x16x32_bf16(
                    af[mf], bf[nf], acc[mf][nf], 0, 0, 0);
        __builtin_amdgcn_s_setprio(0);

        __builtin_amdgcn_s_barrier();
        __builtin_amdgcn_sched_barrier(0);
    }

    const int sel = col0 >> 10;
    __bf16* outp = (sel == 0) ? o0 : (sel == 1) ? o1 : (sel == 2) ? o2 : o3;
    const int cb0 = col0 & 1023;

    if (sel <= 1) {
        // fused xPos rotary + decay fold via tables.
        const bool isQ = (sel == 0);
        const float2* __restrict__ cs = isQ ? csq : csk;
        const float* __restrict__ wd = wdec + (isQ ? 0 : 1024);
        #pragma unroll
        for (int nf = 0; nf < 4; ++nf) {
            const int cl = cb0 + wn * 64 + nf * 16 + (ln & 15);
            const int h = cl >> 6, d0 = cl & 63;
            const float bs = bias[col0 + wn * 64 + nf * 16 + (ln & 15)];
            const bool rot = (d0 < 32);          // wave-uniform per fragment
            const int j = d0 >> 1;
            const bool isEven = ((d0 & 1) == 0);
            #pragma unroll
            for (int mf = 0; mf < 4; ++mf) {
                #pragma unroll
                for (int reg = 0; reg < 4; ++reg) {
                    const int r = row0 + wm * 64 + mf * 16 + (ln >> 4) * 4 + reg;
                    const int s = r & (S - 1);
                    float v = acc[mf][nf][reg] + bs;
                    if (rot) {
                        const float2 t = cs[s * 16 + j];
                        const float partner = __shfl_xor(v, 1, 64);
                        v = isEven ? (v * t.x - partner * t.y)
                                   : (v * t.x + partner * t.y);
                    }
                    v *= wd[h * 64 + (s & 63)];
                    outp[(size_t)r * 1024 + cl] = f2bf(v);
                }
            }
        }
    } else {
        #pragma unroll
        for (int mf = 0; mf < 4; ++mf) {
            #pragma unroll
            for (int nf = 0; nf < 4; ++nf) {
                const int cl = cb0 + wn * 64 + nf * 16 + (ln & 15);
                const float bs = bias[col0 + wn * 64 + nf * 16 + (ln & 15)];
                #pragma unroll
                for (int reg = 0; reg < 4; ++reg) {
                    const int r = row0 + wm * 64 + mf * 16 + (ln >> 4) * 4 + reg;
                    outp[(size_t)r * 1024 + cl] = f2bf(acc[mf][nf][reg] + bs);
                }
            }
        }
    }
}

// ---------------------------------------------------------------------------
// Wo GEMM: 128x64 tile, 256 thr (4 waves 2x2, wave = 64r x 32c), ring-4
// 48KB LDS -> 2 blocks/CU, counted vmcnt(6/3/0), f32 out. Grid (16,32)=512.
// ---------------------------------------------------------------------------
__global__ __launch_bounds__(256) void gemm_wo_kernel(
    const __bf16* __restrict__ A, const __bf16* __restrict__ Bt,
    const float* __restrict__ bias, float* __restrict__ fout)
{
    __shared__ char lds[49152];     // A ring 4x8KB @0, B ring 4x4KB @32768
    constexpr int NTK = 32;

    const int tid = threadIdx.x, wv = tid >> 6, ln = tid & 63;
    const int row0 = blockIdx.y * 128, col0 = blockIdx.x * 64;
    const int wr = (wv >> 1) * 64, wc = (wv & 1) * 32;
    const int lrow = ln & 15, kb = (ln >> 4) * 16;

    f32x4 acc[4][2] = {};

    auto stageA = [&](int k0, char* buf) {
        #pragma unroll
        for (int j = 0; j < 2; ++j) {
            const int r  = j * 64 + (tid >> 2);
            const int cb = ((tid & 3) * 16) ^ (((r >> 1) & 3) << 4);
            GLOAD16((const char*)(A + ((size_t)(row0 + r) << 10) + k0) + cb,
                    buf + j * 4096 + wv * 1024);
        }
    };
    auto stageB = [&](int k0, char* buf) {
        const int r  = tid >> 2;
        const int cb = ((tid & 3) * 16) ^ (((r >> 1) & 3) << 4);
        GLOAD16((const char*)(Bt + ((size_t)(col0 + r) << 10) + k0) + cb,
                buf + wv * 1024);
    };

    #pragma unroll
    for (int tt = 0; tt < 3; ++tt) {
        stageA(tt * 32, lds + tt * 8192);
        stageB(tt * 32, lds + 32768 + tt * 4096);
    }
    asm volatile("s_waitcnt vmcnt(6)" ::: "memory");
    __builtin_amdgcn_s_barrier();
    __builtin_amdgcn_sched_barrier(0);

    for (int t = 0; t < NTK; ++t) {
        const char* ab = lds + (t & 3) * 8192;
        const char* bb = lds + 32768 + (t & 3) * 4096;
        bf16x8 af[4], bf[2];
        #pragma unroll
        for (int mi = 0; mi < 4; ++mi)
            af[mi] = ldsfrag(ab, wr + mi * 16 + lrow, kb);
        #pragma unroll
        for (int ni = 0; ni < 2; ++ni)
            bf[ni] = ldsfrag(bb, wc + ni * 16 + lrow, kb);

        if (t + 3 < NTK) {
            stageA((t + 3) * 32, lds + ((t + 3) & 3) * 8192);
            stageB((t + 3) * 32, lds + 32768 + ((t + 3) & 3) * 4096);
        }

        __builtin_amdgcn_s_setprio(1);
        #pragma unroll
        for (int mi = 0; mi < 4; ++mi)
            #pragma unroll
            for (int ni = 0; ni < 2; ++ni)
                acc[mi][ni] = __builtin_amdgcn_mfma_f32_16x16x32_bf16(
                    af[mi], bf[ni], acc[mi][ni], 0, 0, 0);
        __builtin_amdgcn_s_setprio(0);

        if (t <= NTK - 4)
            asm volatile("s_waitcnt vmcnt(6)" ::: "memory");
        else if (t == NTK - 3)
            asm volatile("s_waitcnt vmcnt(3)" ::: "memory");
        else if (t == NTK - 2)
            asm volatile("s_waitcnt vmcnt(0)" ::: "memory");
        __builtin_amdgcn_s_barrier();
        __builtin_amdgcn_sched_barrier(0);
    }

    #pragma unroll
    for (int mi = 0; mi < 4; ++mi) {
        #pragma unroll
        for (int ni = 0; ni < 2; ++ni) {
            const int c = col0 + wc + ni * 16 + (ln & 15);
            const float bs = bias[c];
            #pragma unroll
            for (int reg = 0; reg < 4; ++reg) {
                const int r = row0 + wr + mi * 16 + (ln >> 4) * 4 + reg;
                fout[(size_t)r * DMODEL + c] = acc[mi][ni][reg] + bs;
            }
        }
    }
}

// ---------------------------------------------------------------------------
// chunk_prep: per (chunk c, h, b): load K-hat,V 64x64 row-major; transpose in
// LDS; write V^T to global; compute U^T[dv][dk] = V^T @ K-hat via MFMA.
// ---------------------------------------------------------------------------
__global__ __launch_bounds__(256) void chunk_prep_kernel(
    const __bf16* __restrict__ kg, const __bf16* __restrict__ vg,
    __bf16* __restrict__ vt, float* __restrict__ U)
{
    __shared__ __bf16 ktile[64][72];
    __shared__ __bf16 vtile[64][72];
    __shared__ __bf16 ktl[64 * 64];    // transposed, swizzled
    __shared__ __bf16 vtl[64 * 64];

    const int c = blockIdx.x, h = blockIdx.y, b = blockIdx.z;
    const int bh = b * 16 + h;
    const int t = threadIdx.x, wv = t >> 6, ln = t & 63;
    const int lrow = ln & 15, lk8 = (ln >> 4) * 8;
    const size_t rowbase = ((size_t)b * S + c * 64) * DMODEL + h * 64;

    #pragma unroll
    for (int p = 0; p < 2; ++p) {
        const int ci = p * 256 + t;
        const int r = ci >> 3, c8 = (ci & 7) * 8;
        *reinterpret_cast<bf16x8*>(&ktile[r][c8]) =
            *reinterpret_cast<const bf16x8*>(&kg[rowbase + (size_t)r * DMODEL + c8]);
        *reinterpret_cast<bf16x8*>(&vtile[r][c8]) =
            *reinterpret_cast<const bf16x8*>(&vg[rowbase + (size_t)r * DMODEL + c8]);
    }
    __syncthreads();

    #pragma unroll
    for (int p = 0; p < 2; ++p) {
        const int ci = p * 256 + t;
        const int d = ci >> 3, s8 = (ci & 7) * 8;
        bf16x8 ok, ov;
        #pragma unroll
        for (int w = 0; w < 8; ++w) {
            ok[w] = ktile[s8 + w][d];
            ov[w] = vtile[s8 + w][d];
        }
        *reinterpret_cast<bf16x8*>(
            &vt[((size_t)bh * 64 + d) * 2048 + c * 64 + s8]) = ov;
        const int off = d * 128 + ((s8 * 2) ^ ((d & 7) << 4));
        *(bf16x8*)((char*)ktl + off) = ok;
        *(bf16x8*)((char*)vtl + off) = ov;
    }
    __syncthreads();

    f32x4 uacc[4] = {};
    #pragma unroll
    for (int ks = 0; ks < 2; ++ks) {
        const int arow = wv * 16 + lrow;
        const bf16x8 af = *(const bf16x8*)((char*)vtl + arow * 128 +
            (((ks * 32 + lk8) * 2) ^ ((arow & 7) << 4)));
        #pragma unroll
        for (int nf = 0; nf < 4; ++nf) {
            const int brow = nf * 16 + lrow;
            const bf16x8 bf_ = *(const bf16x8*)((char*)ktl + brow * 128 +
                (((ks * 32 + lk8) * 2) ^ ((brow & 7) << 4)));
            uacc[nf] = __builtin_amdgcn_mfma_f32_16x16x32_bf16(
                af, bf_, uacc[nf], 0, 0, 0);
        }
    }

    const size_t ub = ((size_t)bh * 32 + c) * 4096;
    #pragma unroll
    for (int nf = 0; nf < 4; ++nf) {
        const int dk = nf * 16 + (ln & 15);
        #pragma unroll
        for (int reg = 0; reg < 4; ++reg) {
            const int dv = wv * 16 + (ln >> 4) * 4 + reg;
            U[ub + dv * 64 + dk] = uacc[nf][reg];
        }
    }
}

// ---------------------------------------------------------------------------
// k2: scan S_c = gamma^64 * S_{c-1} + U_{c-1}. One (dv,dk) cell per thread,
// grid (16,32) = 512 blocks for TLP; 1-deep U prefetch hides L2 latency.
// ---------------------------------------------------------------------------
__global__ __launch_bounds__(256) void chunk_scan_kernel(
    const float* __restrict__ U, __bf16* __restrict__ St)
{
    const int bh = blockIdx.y;
    const int h = bh & 15;
    const float gamma = 1.0f - exp2f(-5.0f - (float)h);
    const float g64 = exp2f(64.0f * __log2f(gamma));
    const int t = threadIdx.x;
    const int dv = blockIdx.x * 4 + (t >> 6);
    const int dk = t & 63;
    const size_t ub = (size_t)bh * 32 * 4096 + (size_t)dv * 64 + dk;

    float s = 0.0f;
    float un = U[ub];                   // c = 0 prefetch
    for (int c = 0; c < 32; ++c) {
        const size_t sb = ub + (size_t)c * 4096;
        St[sb] = f2bf(s);
        const float uc = un;
        if (c < 31) un = U[sb + 4096];  // prefetch c+1 (independent of chain)
        s = g64 * s + uc;
    }
}

// ---------------------------------------------------------------------------
// k3: per-chunk retention + fused GN partial stats; ret stored as bf16.
// ---------------------------------------------------------------------------
__global__ __launch_bounds__(256) void retention_chunk_kernel(
    const __bf16* __restrict__ qg, const __bf16* __restrict__ kg,
    const __bf16* __restrict__ vt, const __bf16* __restrict__ St,
    __bf16* __restrict__ retb, float* __restrict__ part)
{
    __shared__ __bf16 qh[64 * 64];
    __shared__ __bf16 kh[64 * 64];
    __shared__ __bf16 vl[64 * 64];
    __shared__ __bf16 sl[64 * 64];
    __shared__ __bf16 pl[64 * 64];
    __shared__ float rs[4], rq[4];

    const int c = blockIdx.x, h = blockIdx.y, b = blockIdx.z;
    const int bh = b * 16 + h;
    const int t = threadIdx.x, wv = t >> 6, ln = t & 63;
    const int lrow = ln & 15, lk8 = (ln >> 4) * 8;

    const float gamma = 1.0f - exp2f(-5.0f - (float)h);
    const float l2g   = log2f(gamma);
    const float gm64i = exp2f(-64.0f * l2g);
    const size_t rowbase = ((size_t)b * S + c * 64) * DMODEL + h * 64;
    const size_t vtb = (size_t)bh * 64 * 2048 + c * 64;
    const size_t stb = ((size_t)bh * 32 + c) * 4096;

    #pragma unroll
    for (int p = 0; p < 2; ++p) {
        const int ci = p * 256 + t;
        const int r = ci >> 3, c8 = (ci & 7) * 8;
        const int off = r * 128 + ((c8 * 2) ^ ((r & 7) << 4));
        *(bf16x8*)((char*)qh + off) =
            *reinterpret_cast<const bf16x8*>(&qg[rowbase + (size_t)r * DMODEL + c8]);
        *(bf16x8*)((char*)kh + off) =
            *reinterpret_cast<const bf16x8*>(&kg[rowbase + (size_t)r * DMODEL + c8]);
        *(bf16x8*)((char*)vl + off) =
            *reinterpret_cast<const bf16x8*>(&vt[vtb + (size_t)r * 2048 + c8]);
        *(bf16x8*)((char*)sl + off) =
            *reinterpret_cast<const bf16x8*>(&St[stb + r * 64 + c8]);
    }
    __syncthreads();

    f32x4 sacc[4] = {};
    #pragma unroll
    for (int ks = 0; ks < 2; ++ks) {
        const int qrow = wv * 16 + lrow;
        const bf16x8 qf = *(const bf16x8*)((char*)qh + qrow * 128 +
            (((ks * 32 + lk8) * 2) ^ ((qrow & 7) << 4)));
        #pragma unroll
        for (int mi = 0; mi < 4; ++mi) {
            const int krow = mi * 16 + lrow;
            const bf16x8 kf = *(const bf16x8*)((char*)kh + krow * 128 +
                (((ks * 32 + lk8) * 2) ^ ((krow & 7) << 4)));
            sacc[mi] = __builtin_amdgcn_mfma_f32_16x16x32_bf16(
                kf, qf, sacc[mi], 0, 0, 0);
        }
    }

    const int iw = wv * 16 + (ln & 15);
    #pragma unroll
    for (int mi = 0; mi < 4; ++mi) {
        ushort4 pk;
        unsigned short* pkp = (unsigned short*)&pk;
        #pragma unroll
        for (int reg = 0; reg < 4; ++reg) {
            const int j = mi * 16 + (ln >> 4) * 4 + reg;
            const float pv = (j <= iw) ? sacc[mi][reg] * gm64i : 0.0f;
            const __bf16 pb = f2bf(pv);
            pkp[reg] = *(const unsigned short*)&pb;
        }
        const int jb8 = mi * 16 + (ln >> 4) * 4;
        *(ushort4*)((char*)pl + iw * 128 + ((jb8 * 2) ^ ((iw & 7) << 4))) = pk;
    }

    f32x4 acc[4] = {};
    #pragma unroll
    for (int ks = 0; ks < 2; ++ks) {
        const int prow = wv * 16 + lrow;
        const bf16x8 pf = *(const bf16x8*)((char*)pl + prow * 128 +
            (((ks * 32 + lk8) * 2) ^ ((prow & 7) << 4)));
        const bf16x8 qf2 = *(const bf16x8*)((char*)qh + prow * 128 +
            (((ks * 32 + lk8) * 2) ^ ((prow & 7) << 4)));
        #pragma unroll
        for (int nd = 0; nd < 4; ++nd) {
            const int vrow = nd * 16 + lrow;
            const bf16x8 vf = *(const bf16x8*)((char*)vl + vrow * 128 +
                (((ks * 32 + lk8) * 2) ^ ((vrow & 7) << 4)));
            const bf16x8 sf = *(const bf16x8*)((char*)sl + vrow * 128 +
                (((ks * 32 + lk8) * 2) ^ ((vrow & 7) << 4)));
            acc[nd] = __builtin_amdgcn_mfma_f32_16x16x32_bf16(
                pf, vf, acc[nd], 0, 0, 0);
            acc[nd] = __builtin_amdgcn_mfma_f32_16x16x32_bf16(
                qf2, sf, acc[nd], 0, 0, 0);
        }
    }

    const float sc5h = exp2f(5.0f + (float)h);
    float psum = 0.0f, psq = 0.0f;
    #pragma unroll
    for (int reg = 0; reg < 4; ++reg) {
        const int i = c * 64 + wv * 16 + (ln >> 4) * 4 + reg;
        const float omg = 1.0f - exp2f((float)(i + 1) * l2g);
        const float invn = rsqrtf(omg * sc5h);
        #pragma unroll
        for (int nd = 0; nd < 4; ++nd) {
            const float v = acc[nd][reg] * invn;
            retb[((size_t)b * S + i) * DMODEL + h * 64 + nd * 16 + (ln & 15)] =
                f2bf(v);
            psum += v;
            psq  += v * v;
        }
    }
    #pragma unroll
    for (int o = 32; o > 0; o >>= 1) {
        psum += __shfl_down(psum, o, 64);
        psq  += __shfl_down(psq, o, 64);
    }
    if (ln == 0) { rs[wv] = psum; rq[wv] = psq; }
    __syncthreads();
    if (t == 0) {
        part[((size_t)bh * 32 + c) * 2 + 0] = rs[0] + rs[1] + rs[2] + rs[3];
        part[((size_t)bh * 32 + c) * 2 + 1] = rq[0] + rq[1] + rq[2] + rq[3];
    }
}

// ---------------------------------------------------------------------------
// GN finalize + apply, fused: each block reduces its 16 heads' 32 chunk
// partials (part is 8KB, L2-resident), then applies GN * silu(gate).
// ---------------------------------------------------------------------------
__global__ __launch_bounds__(256) void gn_apply_kernel(
    const __bf16* __restrict__ retb, const __bf16* __restrict__ g,
    __bf16* __restrict__ y, const float* __restrict__ part,
    const float* __restrict__ gnw, const float* __restrict__ gnb)
{
    __shared__ float smean[16], srw[16];
    const int tid = threadIdx.x;
    const size_t p = (size_t)blockIdx.x * 256 + tid;  // group of 8
    const size_t el = p * 8;
    const int b = (int)(el >> 21);                    // uniform per block

    // in-block stats reduce: thread t -> head t>>4, chunks {t&15, (t&15)+16}
    {
        const int hh = tid >> 4, sub = tid & 15;
        const int bhh = b * H + hh;
        float s  = part[((size_t)bhh * 32 + sub) * 2 + 0]
                 + part[((size_t)bhh * 32 + sub + 16) * 2 + 0];
        float q2 = part[((size_t)bhh * 32 + sub) * 2 + 1]
                 + part[((size_t)bhh * 32 + sub + 16) * 2 + 1];
        #pragma unroll
        for (int o = 8; o > 0; o >>= 1) {
            s  += __shfl_down(s, o, 16);
            q2 += __shfl_down(q2, o, 16);
        }
        if (sub == 0) {
            const float inv_n = 1.0f / (float)(S * 64);
            const float mean = s * inv_n;
            const float var  = q2 * inv_n - mean * mean;
            smean[hh] = mean;
            srw[hh]   = rsqrtf(var + 1e-5f);
        }
    }
    __syncthreads();

    const int col = (int)(el & (DMODEL - 1));
    const int h   = col >> 6;
    const float mean = smean[h];
    const float w    = srw[h] * gnw[h];
    const float bb   = gnb[h];

    const bf16x8 rv = reinterpret_cast<const bf16x8*>(retb)[p];
    const bf16x8 gv = reinterpret_cast<const bf16x8*>(g)[p];
    bf16x8 o;
    #pragma unroll
    for (int i = 0; i < 8; ++i)
        o[i] = f2bf(((bf2f(rv[i]) - mean) * w + bb) * silu(bf2f(gv[i])));
    reinterpret_cast<bf16x8*>(y)[p] = o;
}

// ---------------------------------------------------------------------------
extern "C" void kernel_launch(void* const* d_in, const int* in_sizes, int n_in,
                              void* d_out, int out_size, void* d_ws, size_t ws_size,
                              hipStream_t stream)
{
    const float* x   = (const float*)d_in[0];
    const float* Wq  = (const float*)d_in[1];
    const float* bq  = (const float*)d_in[2];
    const float* Wk  = (const float*)d_in[3];
    const float* bk  = (const float*)d_in[4];
    const float* Wv  = (const float*)d_in[5];
    const float* bv  = (const float*)d_in[6];
    const float* Wg  = (const float*)d_in[7];
    const float* bg  = (const float*)d_in[8];
    const float* Wo  = (const float*)d_in[9];
    const float* bo  = (const float*)d_in[10];
    const float* gnw = (const float*)d_in[11];
    const float* gnb = (const float*)d_in[12];
    float* out = (float*)d_out;

    // workspace layout
    char* w = (char*)d_ws;
    __bf16* xb      = (__bf16*)w;               w += MAT * 2;            // 8.4MB
    __bf16* wqkvg_t = (__bf16*)w;               w += MAT * 2;            // 8.4MB
    __bf16* wo_t    = (__bf16*)w;               w += (size_t)DMODEL * DMODEL * 2;
    float*  bqkvg   = (float*)w;                w += 4096 * 4;
    __bf16* qb      = (__bf16*)w;               w += MAT * 2;
    __bf16* kb      = (__bf16*)w;               w += MAT * 2;
    __bf16* vb      = (__bf16*)w;               w += MAT * 2;
    __bf16* gb      = (__bf16*)w;               w += MAT * 2;
    __bf16* retb    = (__bf16*)w;               w += MAT * 2;            // bf16
    __bf16* yb      = (__bf16*)w;               w += MAT * 2;
    float*  U       = (float*)w;                w += MAT * 4;            // 16.8MB
    float*  part    = (float*)w;                w += 2048 * 4;
    float2* csq     = (float2*)w;               w += 32768 * 8;          // 256KB
    float2* csk     = (float2*)w;               w += 32768 * 8;          // 256KB
    float*  wdec    = (float*)w;                w += 2048 * 4;           // 8KB
    // aliases over dead buffers:
    __bf16* vt = xb;               // xb dead after QKVG GEMM
    __bf16* St = (__bf16*)wqkvg_t; // wqkvg_t dead after QKVG GEMM (8.4MB)

    // 1) prep (merged cvt_x + transpose_w + pack_bias + rotary/decay tables)
    prep_kernel<<<7320, 256, 0, stream>>>(x, xb, Wq, Wk, Wv, Wg, Wo,
                                          wqkvg_t, wo_t, bq, bk, bv, bg, bqkvg,
                                          csq, csk, wdec);

    // 2) fused QKVG projection GEMM + table-driven rotary/decay epilogue
    gemm_qkvg<<<512, 512, 0, stream>>>(xb, wqkvg_t, bqkvg, qb, kb, vb, gb,
                                       csq, csk, wdec);

    // 3) chunked retention: prep (transpose V + outer product) -> scan -> k3
    {
        dim3 grid(32, 16, 2);
        chunk_prep_kernel<<<grid, 256, 0, stream>>>(kb, vb, vt, U);
    }
    {
        dim3 grid(16, 32);
        chunk_scan_kernel<<<grid, 256, 0, stream>>>(U, St);
    }
    {
        dim3 grid(32, 16, 2);
        retention_chunk_kernel<<<grid, 256, 0, stream>>>(qb, kb, vt, St,
                                                         retb, part);
    }

    // 4) group norm finalize + apply with silu gate (stats fused in-block)
    gn_apply_kernel<<<2048, 256, 0, stream>>>(retb, gb, yb, part, gnw, gnb);

    // 5) output GEMM (4096 x 1024 x 1024), f32 out, 2 blocks/CU
    {
        dim3 grid(16, 32);
        gemm_wo_kernel<<<grid, 256, 0, stream>>>(yb, wo_t, bo, out);
    }
}

// Round 14
// 103.115 us; speedup vs baseline: 1.0626x; 1.0626x over previous
//
#include <hip/hip_runtime.h>
#include <math.h>

constexpr int B = 2;
constexpr int S = 2048;
constexpr int DMODEL = 1024;
constexpr int H = 16;
constexpr int M_TOT = B * S;                     // 4096
constexpr size_t MAT = (size_t)B * S * DMODEL;   // 4,194,304 elements

typedef __attribute__((ext_vector_type(8))) __bf16 bf16x8;
typedef __attribute__((ext_vector_type(4))) float f32x4;

#define GLOAD16(g, l) __builtin_amdgcn_global_load_lds( \
    (const __attribute__((address_space(1))) void*)(g), \
    (__attribute__((address_space(3))) void*)(l), 16, 0, 0)

__device__ __forceinline__ float bf2f(__bf16 v) { return (float)v; }
__device__ __forceinline__ __bf16 f2bf(float v) { return (__bf16)v; }
__device__ __forceinline__ float silu(float z) { return z / (1.0f + expf(-z)); }

// ---------------------------------------------------------------------------
// Merged prep: [0,2048) x fp32->bf16 ; [2048,7168) W transpose+convert ;
// [7168,7184) bias pack.
// ---------------------------------------------------------------------------
__global__ __launch_bounds__(256) void prep_kernel(
    const float* __restrict__ x, __bf16* __restrict__ xb,
    const float* Wq, const float* Wk, const float* Wv, const float* Wg,
    const float* Wo, __bf16* __restrict__ wqkvg_t, __bf16* __restrict__ wo_t,
    const float* bq, const float* bk, const float* bv, const float* bg,
    float* __restrict__ bqkvg)
{
    __shared__ float tile[32][33];
    const int bid = blockIdx.x;
    const int tid = threadIdx.x;

    if (bid < 2048) {
        const size_t p = (size_t)bid * 256 + tid;
        const float4 a = reinterpret_cast<const float4*>(x)[2 * p];
        const float4 b = reinterpret_cast<const float4*>(x)[2 * p + 1];
        bf16x8 o;
        o[0] = f2bf(a.x); o[1] = f2bf(a.y); o[2] = f2bf(a.z); o[3] = f2bf(a.w);
        o[4] = f2bf(b.x); o[5] = f2bf(b.y); o[6] = f2bf(b.z); o[7] = f2bf(b.w);
        reinterpret_cast<bf16x8*>(xb)[p] = o;
    } else if (bid < 7168) {
        const int idx = bid - 2048;
        const int z = idx >> 10;
        const int rem = idx & 1023;
        const int n0 = (rem & 31) * 32, k0 = (rem >> 5) * 32;
        const float* W = (z == 0) ? Wq : (z == 1) ? Wk : (z == 2) ? Wv
                        : (z == 3) ? Wg : Wo;
        const int tx = tid & 31, ty = tid >> 5;
        #pragma unroll
        for (int i = 0; i < 32; i += 8)
            tile[ty + i][tx] = W[(size_t)(k0 + ty + i) * DMODEL + n0 + tx];
        __syncthreads();
        #pragma unroll
        for (int i = 0; i < 32; i += 8) {
            const int n = n0 + ty + i, kk = k0 + tx;
            const __bf16 val = f2bf(tile[tx][ty + i]);
            if (z < 4) wqkvg_t[((size_t)z * 1024 + n) * DMODEL + kk] = val;
            else       wo_t[(size_t)n * DMODEL + kk] = val;
        }
    } else {
        const int i = (bid - 7168) * 256 + tid;
        const float* src = ((i >> 10) == 0) ? bq : ((i >> 10) == 1) ? bk
                          : ((i >> 10) == 2) ? bv : bg;
        bqkvg[i] = src[i & 1023];
    }
}

// ---------------------------------------------------------------------------
// Swizzled LDS layout for 64B (BK=32 bf16) rows.
// Physical slot = logical slot ^ ((row>>1)&3)  -> 2 lanes/bank (free).
// ---------------------------------------------------------------------------
__device__ __forceinline__ bf16x8 ldsfrag(const char* base, int row, int kbyte)
{
    return *(const bf16x8*)(base + row * 64 + (kbyte ^ (((row >> 1) & 3) << 4)));
}

// ---------------------------------------------------------------------------
// QKVG GEMM: 256x128 tile, 512 thr, ring-2 LDS 48KB, 2 blocks/CU, counted
// vmcnt(3). Epilogue fuses xPos rotary + decay fold for q/k. Transcendentals
// reduced ~3x vs R11 via multiplicative recurrences in s: within a thread's
// 16 rows, wdec/cos/sin/sc advance by constant factors (4-aligned reg-quads
// never cross the &63 / &2047 wrap, so the recurrences are exact).
// ---------------------------------------------------------------------------
__global__ __launch_bounds__(512, 4) void gemm_qkvg(
    const __bf16* __restrict__ A, const __bf16* __restrict__ Bt,
    const float* __restrict__ bias,
    __bf16* o0, __bf16* o1, __bf16* o2, __bf16* o3)
{
    __shared__ char lds[49152];     // A 2x16KB @0, B 2x8KB @32768
    constexpr int NTK = 32;         // 1024 / 32

    const int tid = threadIdx.x, wv = tid >> 6, ln = tid & 63;
    const int wm = wv >> 1, wn = wv & 1;

    // bijective XCD swizzle (nwg=512, cpx=64)
    int bid = blockIdx.x;
    bid = (bid & 7) * 64 + (bid >> 3);
    const int bx = bid & 31, by = bid >> 5;
    const int row0 = by * 256, col0 = bx * 128;

    const int lrow = ln & 15;
    const int kb   = (ln >> 4) * 16;

    f32x4 acc[4][4] = {};

    auto stageA = [&](int k0, char* buf) {
        #pragma unroll
        for (int j = 0; j < 2; ++j) {
            const int r  = j * 128 + (tid >> 2);
            const int cb = ((tid & 3) * 16) ^ (((r >> 1) & 3) << 4);
            GLOAD16((const char*)(A + ((size_t)(row0 + r) << 10) + k0) + cb,
                    buf + j * 8192 + wv * 1024);
        }
    };
    auto stageB = [&](int k0, char* buf) {
        const int r  = tid >> 2;
        const int cb = ((tid & 3) * 16) ^ (((r >> 1) & 3) << 4);
        GLOAD16((const char*)(Bt + ((size_t)(col0 + r) << 10) + k0) + cb,
                buf + wv * 1024);
    };

    stageA(0, lds);
    stageB(0, lds + 32768);

    for (int t = 0; t < NTK; ++t) {
        char* ab = lds + (t & 1) * 16384;
        char* bb = lds + 32768 + (t & 1) * 8192;

        if (t + 1 < NTK) {
            stageA((t + 1) * 32, lds + ((t + 1) & 1) * 16384);
            stageB((t + 1) * 32, lds + 32768 + ((t + 1) & 1) * 8192);
            asm volatile("s_waitcnt vmcnt(3)" ::: "memory");
        } else {
            asm volatile("s_waitcnt vmcnt(0)" ::: "memory");
        }
        __builtin_amdgcn_s_barrier();
        __builtin_amdgcn_sched_barrier(0);

        bf16x8 af[4], bf[4];
        #pragma unroll
        for (int mf = 0; mf < 4; ++mf)
            af[mf] = ldsfrag(ab, wm * 64 + mf * 16 + lrow, kb);
        #pragma unroll
        for (int nf = 0; nf < 4; ++nf)
            bf[nf] = ldsfrag(bb, wn * 64 + nf * 16 + lrow, kb);

        __builtin_amdgcn_s_setprio(1);
        #pragma unroll
        for (int mf = 0; mf < 4; ++mf)
            #pragma unroll
            for (int nf = 0; nf < 4; ++nf)
                acc[mf][nf] = __builtin_amdgcn_mfma_f32_16x16x32_bf16(
                    af[mf], bf[nf], acc[mf][nf], 0, 0, 0);
        __builtin_amdgcn_s_setprio(0);

        __builtin_amdgcn_s_barrier();
        __builtin_amdgcn_sched_barrier(0);
    }

    const int sel = col0 >> 10;
    __bf16* outp = (sel == 0) ? o0 : (sel == 1) ? o1 : (sel == 2) ? o2 : o3;
    const int cb0 = col0 & 1023;

    if (sel <= 1) {
        const bool isQ = (sel == 0);
        #pragma unroll
        for (int nf = 0; nf < 4; ++nf) {
            const int cl = cb0 + wn * 64 + nf * 16 + (ln & 15);
            const int h = cl >> 6, d0 = cl & 63;
            const float bs = bias[col0 + wn * 64 + nf * 16 + (ln & 15)];
            const float l2g = __log2f(1.0f - exp2f(-5.0f - (float)h));
            const float dstep = exp2f(isQ ? l2g : -l2g);   // gamma or 1/gamma
            const bool rot = (d0 < 32);          // wave-uniform per fragment
            const bool isEven = ((d0 & 1) == 0);
            float invf = 0.0f, l2base = 0.0f, cd = 0.0f, sd = 0.0f,
                  scstep = 0.0f;
            if (rot) {
                const int j = d0 >> 1;
                invf = exp2f(-0.830482024f * (float)j);  // 10000^(-j/16)
                l2base = __log2f(((float)(2 * j) + 12.8f) * (1.0f / 44.8f));
                if (!isQ) l2base = -l2base;
                cd = __cosf(invf);
                sd = __sinf(invf);
                scstep = exp2f(l2base * (1.0f / 512.0f));
            }
            #pragma unroll
            for (int mf = 0; mf < 4; ++mf) {
                const int r0 = row0 + wm * 64 + mf * 16 + (ln >> 4) * 4;
                const int s0 = r0 & (S - 1);
                const int sl0 = s0 & 63;
                float wd = exp2f((isQ ? (float)(sl0 + 1)
                                      : (float)(63 - sl0)) * l2g);
                float cc = 0.0f, sn = 0.0f, sc = 0.0f;
                if (rot) {
                    const float th0 = (float)s0 * invf;
                    cc = __cosf(th0);
                    sn = __sinf(th0);
                    sc = exp2f(l2base * ((float)s0 - 1024.0f) * (1.0f / 512.0f));
                }
                #pragma unroll
                for (int reg = 0; reg < 4; ++reg) {
                    float v = acc[mf][nf][reg] + bs;
                    if (rot) {
                        const float partner = __shfl_xor(v, 1, 64);
                        v = isEven ? (v * cc - partner * sn)
                                   : (v * cc + partner * sn);
                        v *= sc;
                    }
                    outp[(size_t)(r0 + reg) * 1024 + cl] = f2bf(v * wd);
                    // advance recurrences (s -> s+1)
                    wd *= dstep;
                    if (rot) {
                        const float cn = cc * cd - sn * sd;
                        sn = sn * cd + cc * sd;
                        cc = cn;
                        sc *= scstep;
                    }
                }
            }
        }
    } else {
        #pragma unroll
        for (int mf = 0; mf < 4; ++mf) {
            #pragma unroll
            for (int nf = 0; nf < 4; ++nf) {
                const int cl = cb0 + wn * 64 + nf * 16 + (ln & 15);
                const float bs = bias[col0 + wn * 64 + nf * 16 + (ln & 15)];
                #pragma unroll
                for (int reg = 0; reg < 4; ++reg) {
                    const int r = row0 + wm * 64 + mf * 16 + (ln >> 4) * 4 + reg;
                    outp[(size_t)r * 1024 + cl] = f2bf(acc[mf][nf][reg] + bs);
                }
            }
        }
    }
}

// ---------------------------------------------------------------------------
// Wo GEMM: 128x64 tile, 256 thr (4 waves 2x2, wave = 64r x 32c), ring-4
// 48KB LDS -> 2 blocks/CU, counted vmcnt(6/3/0), f32 out. Grid (16,32)=512.
// ---------------------------------------------------------------------------
__global__ __launch_bounds__(256) void gemm_wo_kernel(
    const __bf16* __restrict__ A, const __bf16* __restrict__ Bt,
    const float* __restrict__ bias, float* __restrict__ fout)
{
    __shared__ char lds[49152];     // A ring 4x8KB @0, B ring 4x4KB @32768
    constexpr int NTK = 32;

    const int tid = threadIdx.x, wv = tid >> 6, ln = tid & 63;
    const int row0 = blockIdx.y * 128, col0 = blockIdx.x * 64;
    const int wr = (wv >> 1) * 64, wc = (wv & 1) * 32;
    const int lrow = ln & 15, kb = (ln >> 4) * 16;

    f32x4 acc[4][2] = {};

    auto stageA = [&](int k0, char* buf) {
        #pragma unroll
        for (int j = 0; j < 2; ++j) {
            const int r  = j * 64 + (tid >> 2);
            const int cb = ((tid & 3) * 16) ^ (((r >> 1) & 3) << 4);
            GLOAD16((const char*)(A + ((size_t)(row0 + r) << 10) + k0) + cb,
                    buf + j * 4096 + wv * 1024);
        }
    };
    auto stageB = [&](int k0, char* buf) {
        const int r  = tid >> 2;
        const int cb = ((tid & 3) * 16) ^ (((r >> 1) & 3) << 4);
        GLOAD16((const char*)(Bt + ((size_t)(col0 + r) << 10) + k0) + cb,
                buf + wv * 1024);
    };

    #pragma unroll
    for (int tt = 0; tt < 3; ++tt) {
        stageA(tt * 32, lds + tt * 8192);
        stageB(tt * 32, lds + 32768 + tt * 4096);
    }
    asm volatile("s_waitcnt vmcnt(6)" ::: "memory");
    __builtin_amdgcn_s_barrier();
    __builtin_amdgcn_sched_barrier(0);

    for (int t = 0; t < NTK; ++t) {
        const char* ab = lds + (t & 3) * 8192;
        const char* bb = lds + 32768 + (t & 3) * 4096;
        bf16x8 af[4], bf[2];
        #pragma unroll
        for (int mi = 0; mi < 4; ++mi)
            af[mi] = ldsfrag(ab, wr + mi * 16 + lrow, kb);
        #pragma unroll
        for (int ni = 0; ni < 2; ++ni)
            bf[ni] = ldsfrag(bb, wc + ni * 16 + lrow, kb);

        if (t + 3 < NTK) {
            stageA((t + 3) * 32, lds + ((t + 3) & 3) * 8192);
            stageB((t + 3) * 32, lds + 32768 + ((t + 3) & 3) * 4096);
        }

        __builtin_amdgcn_s_setprio(1);
        #pragma unroll
        for (int mi = 0; mi < 4; ++mi)
            #pragma unroll
            for (int ni = 0; ni < 2; ++ni)
                acc[mi][ni] = __builtin_amdgcn_mfma_f32_16x16x32_bf16(
                    af[mi], bf[ni], acc[mi][ni], 0, 0, 0);
        __builtin_amdgcn_s_setprio(0);

        if (t <= NTK - 4)
            asm volatile("s_waitcnt vmcnt(6)" ::: "memory");
        else if (t == NTK - 3)
            asm volatile("s_waitcnt vmcnt(3)" ::: "memory");
        else if (t == NTK - 2)
            asm volatile("s_waitcnt vmcnt(0)" ::: "memory");
        __builtin_amdgcn_s_barrier();
        __builtin_amdgcn_sched_barrier(0);
    }

    #pragma unroll
    for (int mi = 0; mi < 4; ++mi) {
        #pragma unroll
        for (int ni = 0; ni < 2; ++ni) {
            const int c = col0 + wc + ni * 16 + (ln & 15);
            const float bs = bias[c];
            #pragma unroll
            for (int reg = 0; reg < 4; ++reg) {
                const int r = row0 + wr + mi * 16 + (ln >> 4) * 4 + reg;
                fout[(size_t)r * DMODEL + c] = acc[mi][ni][reg] + bs;
            }
        }
    }
}

// ---------------------------------------------------------------------------
// chunk_prep: per (chunk c, h, b): load K-hat,V 64x64 row-major; transpose in
// LDS; write V^T to global; compute U^T[dv][dk] = V^T @ K-hat via MFMA.
// ---------------------------------------------------------------------------
__global__ __launch_bounds__(256) void chunk_prep_kernel(
    const __bf16* __restrict__ kg, const __bf16* __restrict__ vg,
    __bf16* __restrict__ vt, float* __restrict__ U)
{
    __shared__ __bf16 ktile[64][72];
    __shared__ __bf16 vtile[64][72];
    __shared__ __bf16 ktl[64 * 64];    // transposed, swizzled
    __shared__ __bf16 vtl[64 * 64];

    const int c = blockIdx.x, h = blockIdx.y, b = blockIdx.z;
    const int bh = b * 16 + h;
    const int t = threadIdx.x, wv = t >> 6, ln = t & 63;
    const int lrow = ln & 15, lk8 = (ln >> 4) * 8;
    const size_t rowbase = ((size_t)b * S + c * 64) * DMODEL + h * 64;

    #pragma unroll
    for (int p = 0; p < 2; ++p) {
        const int ci = p * 256 + t;
        const int r = ci >> 3, c8 = (ci & 7) * 8;
        *reinterpret_cast<bf16x8*>(&ktile[r][c8]) =
            *reinterpret_cast<const bf16x8*>(&kg[rowbase + (size_t)r * DMODEL + c8]);
        *reinterpret_cast<bf16x8*>(&vtile[r][c8]) =
            *reinterpret_cast<const bf16x8*>(&vg[rowbase + (size_t)r * DMODEL + c8]);
    }
    __syncthreads();

    #pragma unroll
    for (int p = 0; p < 2; ++p) {
        const int ci = p * 256 + t;
        const int d = ci >> 3, s8 = (ci & 7) * 8;
        bf16x8 ok, ov;
        #pragma unroll
        for (int w = 0; w < 8; ++w) {
            ok[w] = ktile[s8 + w][d];
            ov[w] = vtile[s8 + w][d];
        }
        *reinterpret_cast<bf16x8*>(
            &vt[((size_t)bh * 64 + d) * 2048 + c * 64 + s8]) = ov;
        const int off = d * 128 + ((s8 * 2) ^ ((d & 7) << 4));
        *(bf16x8*)((char*)ktl + off) = ok;
        *(bf16x8*)((char*)vtl + off) = ov;
    }
    __syncthreads();

    f32x4 uacc[4] = {};
    #pragma unroll
    for (int ks = 0; ks < 2; ++ks) {
        const int arow = wv * 16 + lrow;
        const bf16x8 af = *(const bf16x8*)((char*)vtl + arow * 128 +
            (((ks * 32 + lk8) * 2) ^ ((arow & 7) << 4)));
        #pragma unroll
        for (int nf = 0; nf < 4; ++nf) {
            const int brow = nf * 16 + lrow;
            const bf16x8 bf_ = *(const bf16x8*)((char*)ktl + brow * 128 +
                (((ks * 32 + lk8) * 2) ^ ((brow & 7) << 4)));
            uacc[nf] = __builtin_amdgcn_mfma_f32_16x16x32_bf16(
                af, bf_, uacc[nf], 0, 0, 0);
        }
    }

    const size_t ub = ((size_t)bh * 32 + c) * 4096;
    #pragma unroll
    for (int nf = 0; nf < 4; ++nf) {
        const int dk = nf * 16 + (ln & 15);
        #pragma unroll
        for (int reg = 0; reg < 4; ++reg) {
            const int dv = wv * 16 + (ln >> 4) * 4 + reg;
            U[ub + dv * 64 + dk] = uacc[nf][reg];
        }
    }
}

// ---------------------------------------------------------------------------
// k2: scan S_c = gamma^64 * S_{c-1} + U_{c-1}. One (dv,dk) cell per thread,
// grid (16,32) = 512 blocks for TLP; 1-deep U prefetch hides L2 latency.
// ---------------------------------------------------------------------------
__global__ __launch_bounds__(256) void chunk_scan_kernel(
    const float* __restrict__ U, __bf16* __restrict__ St)
{
    const int bh = blockIdx.y;
    const int h = bh & 15;
    const float gamma = 1.0f - exp2f(-5.0f - (float)h);
    const float g64 = exp2f(64.0f * __log2f(gamma));
    const int t = threadIdx.x;
    const int dv = blockIdx.x * 4 + (t >> 6);
    const int dk = t & 63;
    const size_t ub = (size_t)bh * 32 * 4096 + (size_t)dv * 64 + dk;

    float s = 0.0f;
    float un = U[ub];                   // c = 0 prefetch
    for (int c = 0; c < 32; ++c) {
        const size_t sb = ub + (size_t)c * 4096;
        St[sb] = f2bf(s);
        const float uc = un;
        if (c < 31) un = U[sb + 4096];  // prefetch c+1 (independent of chain)
        s = g64 * s + uc;
    }
}

// ---------------------------------------------------------------------------
// k3: per-chunk retention + fused GN partial stats; ret stored as bf16.
// ---------------------------------------------------------------------------
__global__ __launch_bounds__(256) void retention_chunk_kernel(
    const __bf16* __restrict__ qg, const __bf16* __restrict__ kg,
    const __bf16* __restrict__ vt, const __bf16* __restrict__ St,
    __bf16* __restrict__ retb, float* __restrict__ part)
{
    __shared__ __bf16 qh[64 * 64];
    __shared__ __bf16 kh[64 * 64];
    __shared__ __bf16 vl[64 * 64];
    __shared__ __bf16 sl[64 * 64];
    __shared__ __bf16 pl[64 * 64];
    __shared__ float rs[4], rq[4];

    const int c = blockIdx.x, h = blockIdx.y, b = blockIdx.z;
    const int bh = b * 16 + h;
    const int t = threadIdx.x, wv = t >> 6, ln = t & 63;
    const int lrow = ln & 15, lk8 = (ln >> 4) * 8;

    const float gamma = 1.0f - exp2f(-5.0f - (float)h);
    const float l2g   = log2f(gamma);
    const float gm64i = exp2f(-64.0f * l2g);
    const size_t rowbase = ((size_t)b * S + c * 64) * DMODEL + h * 64;
    const size_t vtb = (size_t)bh * 64 * 2048 + c * 64;
    const size_t stb = ((size_t)bh * 32 + c) * 4096;

    #pragma unroll
    for (int p = 0; p < 2; ++p) {
        const int ci = p * 256 + t;
        const int r = ci >> 3, c8 = (ci & 7) * 8;
        const int off = r * 128 + ((c8 * 2) ^ ((r & 7) << 4));
        *(bf16x8*)((char*)qh + off) =
            *reinterpret_cast<const bf16x8*>(&qg[rowbase + (size_t)r * DMODEL + c8]);
        *(bf16x8*)((char*)kh + off) =
            *reinterpret_cast<const bf16x8*>(&kg[rowbase + (size_t)r * DMODEL + c8]);
        *(bf16x8*)((char*)vl + off) =
            *reinterpret_cast<const bf16x8*>(&vt[vtb + (size_t)r * 2048 + c8]);
        *(bf16x8*)((char*)sl + off) =
            *reinterpret_cast<const bf16x8*>(&St[stb + r * 64 + c8]);
    }
    __syncthreads();

    f32x4 sacc[4] = {};
    #pragma unroll
    for (int ks = 0; ks < 2; ++ks) {
        const int qrow = wv * 16 + lrow;
        const bf16x8 qf = *(const bf16x8*)((char*)qh + qrow * 128 +
            (((ks * 32 + lk8) * 2) ^ ((qrow & 7) << 4)));
        #pragma unroll
        for (int mi = 0; mi < 4; ++mi) {
            const int krow = mi * 16 + lrow;
            const bf16x8 kf = *(const bf16x8*)((char*)kh + krow * 128 +
                (((ks * 32 + lk8) * 2) ^ ((krow & 7) << 4)));
            sacc[mi] = __builtin_amdgcn_mfma_f32_16x16x32_bf16(
                kf, qf, sacc[mi], 0, 0, 0);
        }
    }

    const int iw = wv * 16 + (ln & 15);
    #pragma unroll
    for (int mi = 0; mi < 4; ++mi) {
        ushort4 pk;
        unsigned short* pkp = (unsigned short*)&pk;
        #pragma unroll
        for (int reg = 0; reg < 4; ++reg) {
            const int j = mi * 16 + (ln >> 4) * 4 + reg;
            const float pv = (j <= iw) ? sacc[mi][reg] * gm64i : 0.0f;
            const __bf16 pb = f2bf(pv);
            pkp[reg] = *(const unsigned short*)&pb;
        }
        const int jb8 = mi * 16 + (ln >> 4) * 4;
        *(ushort4*)((char*)pl + iw * 128 + ((jb8 * 2) ^ ((iw & 7) << 4))) = pk;
    }

    f32x4 acc[4] = {};
    #pragma unroll
    for (int ks = 0; ks < 2; ++ks) {
        const int prow = wv * 16 + lrow;
        const bf16x8 pf = *(const bf16x8*)((char*)pl + prow * 128 +
            (((ks * 32 + lk8) * 2) ^ ((prow & 7) << 4)));
        const bf16x8 qf2 = *(const bf16x8*)((char*)qh + prow * 128 +
            (((ks * 32 + lk8) * 2) ^ ((prow & 7) << 4)));
        #pragma unroll
        for (int nd = 0; nd < 4; ++nd) {
            const int vrow = nd * 16 + lrow;
            const bf16x8 vf = *(const bf16x8*)((char*)vl + vrow * 128 +
                (((ks * 32 + lk8) * 2) ^ ((vrow & 7) << 4)));
            const bf16x8 sf = *(const bf16x8*)((char*)sl + vrow * 128 +
                (((ks * 32 + lk8) * 2) ^ ((vrow & 7) << 4)));
            acc[nd] = __builtin_amdgcn_mfma_f32_16x16x32_bf16(
                pf, vf, acc[nd], 0, 0, 0);
            acc[nd] = __builtin_amdgcn_mfma_f32_16x16x32_bf16(
                qf2, sf, acc[nd], 0, 0, 0);
        }
    }

    const float sc5h = exp2f(5.0f + (float)h);
    float psum = 0.0f, psq = 0.0f;
    #pragma unroll
    for (int reg = 0; reg < 4; ++reg) {
        const int i = c * 64 + wv * 16 + (ln >> 4) * 4 + reg;
        const float omg = 1.0f - exp2f((float)(i + 1) * l2g);
        const float invn = rsqrtf(omg * sc5h);
        #pragma unroll
        for (int nd = 0; nd < 4; ++nd) {
            const float v = acc[nd][reg] * invn;
            retb[((size_t)b * S + i) * DMODEL + h * 64 + nd * 16 + (ln & 15)] =
                f2bf(v);
            psum += v;
            psq  += v * v;
        }
    }
    #pragma unroll
    for (int o = 32; o > 0; o >>= 1) {
        psum += __shfl_down(psum, o, 64);
        psq  += __shfl_down(psq, o, 64);
    }
    if (ln == 0) { rs[wv] = psum; rq[wv] = psq; }
    __syncthreads();
    if (t == 0) {
        part[((size_t)bh * 32 + c) * 2 + 0] = rs[0] + rs[1] + rs[2] + rs[3];
        part[((size_t)bh * 32 + c) * 2 + 1] = rq[0] + rq[1] + rq[2] + rq[3];
    }
}

// ---------------------------------------------------------------------------
// GN finalize + apply, fused: each block reduces its 16 heads' 32 chunk
// partials (part is 8KB, L2-resident), then applies GN * silu(gate).
// ---------------------------------------------------------------------------
__global__ __launch_bounds__(256) void gn_apply_kernel(
    const __bf16* __restrict__ retb, const __bf16* __restrict__ g,
    __bf16* __restrict__ y, const float* __restrict__ part,
    const float* __restrict__ gnw, const float* __restrict__ gnb)
{
    __shared__ float smean[16], srw[16];
    const int tid = threadIdx.x;
    const size_t p = (size_t)blockIdx.x * 256 + tid;  // group of 8
    const size_t el = p * 8;
    const int b = (int)(el >> 21);                    // uniform per block

    // in-block stats reduce: thread t -> head t>>4, chunks {t&15, (t&15)+16}
    {
        const int hh = tid >> 4, sub = tid & 15;
        const int bhh = b * H + hh;
        float s  = part[((size_t)bhh * 32 + sub) * 2 + 0]
                 + part[((size_t)bhh * 32 + sub + 16) * 2 + 0];
        float q2 = part[((size_t)bhh * 32 + sub) * 2 + 1]
                 + part[((size_t)bhh * 32 + sub + 16) * 2 + 1];
        #pragma unroll
        for (int o = 8; o > 0; o >>= 1) {
            s  += __shfl_down(s, o, 16);
            q2 += __shfl_down(q2, o, 16);
        }
        if (sub == 0) {
            const float inv_n = 1.0f / (float)(S * 64);
            const float mean = s * inv_n;
            const float var  = q2 * inv_n - mean * mean;
            smean[hh] = mean;
            srw[hh]   = rsqrtf(var + 1e-5f);
        }
    }
    __syncthreads();

    const int col = (int)(el & (DMODEL - 1));
    const int h   = col >> 6;
    const float mean = smean[h];
    const float w    = srw[h] * gnw[h];
    const float bb   = gnb[h];

    const bf16x8 rv = reinterpret_cast<const bf16x8*>(retb)[p];
    const bf16x8 gv = reinterpret_cast<const bf16x8*>(g)[p];
    bf16x8 o;
    #pragma unroll
    for (int i = 0; i < 8; ++i)
        o[i] = f2bf(((bf2f(rv[i]) - mean) * w + bb) * silu(bf2f(gv[i])));
    reinterpret_cast<bf16x8*>(y)[p] = o;
}

// ---------------------------------------------------------------------------
extern "C" void kernel_launch(void* const* d_in, const int* in_sizes, int n_in,
                              void* d_out, int out_size, void* d_ws, size_t ws_size,
                              hipStream_t stream)
{
    const float* x   = (const float*)d_in[0];
    const float* Wq  = (const float*)d_in[1];
    const float* bq  = (const float*)d_in[2];
    const float* Wk  = (const float*)d_in[3];
    const float* bk  = (const float*)d_in[4];
    const float* Wv  = (const float*)d_in[5];
    const float* bv  = (const float*)d_in[6];
    const float* Wg  = (const float*)d_in[7];
    const float* bg  = (const float*)d_in[8];
    const float* Wo  = (const float*)d_in[9];
    const float* bo  = (const float*)d_in[10];
    const float* gnw = (const float*)d_in[11];
    const float* gnb = (const float*)d_in[12];
    float* out = (float*)d_out;

    // workspace layout
    char* w = (char*)d_ws;
    __bf16* xb      = (__bf16*)w;               w += MAT * 2;            // 8.4MB
    __bf16* wqkvg_t = (__bf16*)w;               w += MAT * 2;            // 8.4MB
    __bf16* wo_t    = (__bf16*)w;               w += (size_t)DMODEL * DMODEL * 2;
    float*  bqkvg   = (float*)w;                w += 4096 * 4;
    __bf16* qb      = (__bf16*)w;               w += MAT * 2;
    __bf16* kb      = (__bf16*)w;               w += MAT * 2;
    __bf16* vb      = (__bf16*)w;               w += MAT * 2;
    __bf16* gb      = (__bf16*)w;               w += MAT * 2;
    __bf16* retb    = (__bf16*)w;               w += MAT * 2;            // bf16
    __bf16* yb      = (__bf16*)w;               w += MAT * 2;
    float*  U       = (float*)w;                w += MAT * 4;            // 16.8MB
    float*  part    = (float*)w;                w += 2048 * 4;
    // aliases over dead buffers:
    __bf16* vt = xb;               // xb dead after QKVG GEMM
    __bf16* St = (__bf16*)wqkvg_t; // wqkvg_t dead after QKVG GEMM (8.4MB)

    // 1) prep (merged cvt_x + transpose_w + pack_bias)
    prep_kernel<<<7184, 256, 0, stream>>>(x, xb, Wq, Wk, Wv, Wg, Wo,
                                          wqkvg_t, wo_t, bq, bk, bv, bg, bqkvg);

    // 2) fused QKVG projection GEMM + recurrence-based rotary/decay epilogue
    gemm_qkvg<<<512, 512, 0, stream>>>(xb, wqkvg_t, bqkvg, qb, kb, vb, gb);

    // 3) chunked retention: prep (transpose V + outer product) -> scan -> k3
    {
        dim3 grid(32, 16, 2);
        chunk_prep_kernel<<<grid, 256, 0, stream>>>(kb, vb, vt, U);
    }
    {
        dim3 grid(16, 32);
        chunk_scan_kernel<<<grid, 256, 0, stream>>>(U, St);
    }
    {
        dim3 grid(32, 16, 2);
        retention_chunk_kernel<<<grid, 256, 0, stream>>>(qb, kb, vt, St,
                                                         retb, part);
    }

    // 4) group norm finalize + apply with silu gate (stats fused in-block)
    gn_apply_kernel<<<2048, 256, 0, stream>>>(retb, gb, yb, part, gnw, gnb);

    // 5) output GEMM (4096 x 1024 x 1024), f32 out, 2 blocks/CU
    {
        dim3 grid(16, 32);
        gemm_wo_kernel<<<grid, 256, 0, stream>>>(yb, wo_t, bo, out);
    }
}

// Round 15
// 102.696 us; speedup vs baseline: 1.0669x; 1.0041x over previous
//
#include <hip/hip_runtime.h>
#include <math.h>

constexpr int B = 2;
constexpr int S = 2048;
constexpr int DMODEL = 1024;
constexpr int H = 16;
constexpr int M_TOT = B * S;                     // 4096
constexpr size_t MAT = (size_t)B * S * DMODEL;   // 4,194,304 elements

typedef __attribute__((ext_vector_type(8))) __bf16 bf16x8;
typedef __attribute__((ext_vector_type(4))) float f32x4;

#define GLOAD16(g, l) __builtin_amdgcn_global_load_lds( \
    (const __attribute__((address_space(1))) void*)(g), \
    (__attribute__((address_space(3))) void*)(l), 16, 0, 0)

__device__ __forceinline__ float bf2f(__bf16 v) { return (float)v; }
__device__ __forceinline__ __bf16 f2bf(float v) { return (__bf16)v; }
__device__ __forceinline__ float silu(float z) { return z / (1.0f + expf(-z)); }

// ---------------------------------------------------------------------------
// Merged prep: [0,2048) x fp32->bf16 ; [2048,7168) W transpose+convert ;
// [7168,7184) bias pack.
// ---------------------------------------------------------------------------
__global__ __launch_bounds__(256) void prep_kernel(
    const float* __restrict__ x, __bf16* __restrict__ xb,
    const float* Wq, const float* Wk, const float* Wv, const float* Wg,
    const float* Wo, __bf16* __restrict__ wqkvg_t, __bf16* __restrict__ wo_t,
    const float* bq, const float* bk, const float* bv, const float* bg,
    float* __restrict__ bqkvg)
{
    __shared__ float tile[32][33];
    const int bid = blockIdx.x;
    const int tid = threadIdx.x;

    if (bid < 2048) {
        const size_t p = (size_t)bid * 256 + tid;
        const float4 a = reinterpret_cast<const float4*>(x)[2 * p];
        const float4 b = reinterpret_cast<const float4*>(x)[2 * p + 1];
        bf16x8 o;
        o[0] = f2bf(a.x); o[1] = f2bf(a.y); o[2] = f2bf(a.z); o[3] = f2bf(a.w);
        o[4] = f2bf(b.x); o[5] = f2bf(b.y); o[6] = f2bf(b.z); o[7] = f2bf(b.w);
        reinterpret_cast<bf16x8*>(xb)[p] = o;
    } else if (bid < 7168) {
        const int idx = bid - 2048;
        const int z = idx >> 10;
        const int rem = idx & 1023;
        const int n0 = (rem & 31) * 32, k0 = (rem >> 5) * 32;
        const float* W = (z == 0) ? Wq : (z == 1) ? Wk : (z == 2) ? Wv
                        : (z == 3) ? Wg : Wo;
        const int tx = tid & 31, ty = tid >> 5;
        #pragma unroll
        for (int i = 0; i < 32; i += 8)
            tile[ty + i][tx] = W[(size_t)(k0 + ty + i) * DMODEL + n0 + tx];
        __syncthreads();
        #pragma unroll
        for (int i = 0; i < 32; i += 8) {
            const int n = n0 + ty + i, kk = k0 + tx;
            const __bf16 val = f2bf(tile[tx][ty + i]);
            if (z < 4) wqkvg_t[((size_t)z * 1024 + n) * DMODEL + kk] = val;
            else       wo_t[(size_t)n * DMODEL + kk] = val;
        }
    } else {
        const int i = (bid - 7168) * 256 + tid;
        const float* src = ((i >> 10) == 0) ? bq : ((i >> 10) == 1) ? bk
                          : ((i >> 10) == 2) ? bv : bg;
        bqkvg[i] = src[i & 1023];
    }
}

// ---------------------------------------------------------------------------
// Swizzled LDS layout for 64B (BK=32 bf16) rows.
// Physical slot = logical slot ^ ((row>>1)&3)  -> 2 lanes/bank (free).
// ---------------------------------------------------------------------------
__device__ __forceinline__ bf16x8 ldsfrag(const char* base, int row, int kbyte)
{
    return *(const bf16x8*)(base + row * 64 + (kbyte ^ (((row >> 1) & 3) << 4)));
}

// ---------------------------------------------------------------------------
// QKVG GEMM: 256x128 tile, 512 thr, ring-2 LDS 48KB, 2 blocks/CU, counted
// vmcnt(3). Epilogue fuses xPos rotary + decay fold for q/k with fully
// hoisted transcendentals (~27/thread): h is thread-constant (64-aligned
// column band), a thread's 16 rows live in one 64-aligned s-band (no wraps),
// so wd/cos/sin/sc all advance by fixed per-reg and per-mf multiplicative
// steps from a single init.
// ---------------------------------------------------------------------------
__global__ __launch_bounds__(512, 4) void gemm_qkvg(
    const __bf16* __restrict__ A, const __bf16* __restrict__ Bt,
    const float* __restrict__ bias,
    __bf16* o0, __bf16* o1, __bf16* o2, __bf16* o3)
{
    __shared__ char lds[49152];     // A 2x16KB @0, B 2x8KB @32768
    constexpr int NTK = 32;         // 1024 / 32

    const int tid = threadIdx.x, wv = tid >> 6, ln = tid & 63;
    const int wm = wv >> 1, wn = wv & 1;

    // bijective XCD swizzle (nwg=512, cpx=64)
    int bid = blockIdx.x;
    bid = (bid & 7) * 64 + (bid >> 3);
    const int bx = bid & 31, by = bid >> 5;
    const int row0 = by * 256, col0 = bx * 128;

    const int lrow = ln & 15;
    const int kb   = (ln >> 4) * 16;

    f32x4 acc[4][4] = {};

    auto stageA = [&](int k0, char* buf) {
        #pragma unroll
        for (int j = 0; j < 2; ++j) {
            const int r  = j * 128 + (tid >> 2);
            const int cb = ((tid & 3) * 16) ^ (((r >> 1) & 3) << 4);
            GLOAD16((const char*)(A + ((size_t)(row0 + r) << 10) + k0) + cb,
                    buf + j * 8192 + wv * 1024);
        }
    };
    auto stageB = [&](int k0, char* buf) {
        const int r  = tid >> 2;
        const int cb = ((tid & 3) * 16) ^ (((r >> 1) & 3) << 4);
        GLOAD16((const char*)(Bt + ((size_t)(col0 + r) << 10) + k0) + cb,
                buf + wv * 1024);
    };

    stageA(0, lds);
    stageB(0, lds + 32768);

    for (int t = 0; t < NTK; ++t) {
        char* ab = lds + (t & 1) * 16384;
        char* bb = lds + 32768 + (t & 1) * 8192;

        if (t + 1 < NTK) {
            stageA((t + 1) * 32, lds + ((t + 1) & 1) * 16384);
            stageB((t + 1) * 32, lds + 32768 + ((t + 1) & 1) * 8192);
            asm volatile("s_waitcnt vmcnt(3)" ::: "memory");
        } else {
            asm volatile("s_waitcnt vmcnt(0)" ::: "memory");
        }
        __builtin_amdgcn_s_barrier();
        __builtin_amdgcn_sched_barrier(0);

        bf16x8 af[4], bf[4];
        #pragma unroll
        for (int mf = 0; mf < 4; ++mf)
            af[mf] = ldsfrag(ab, wm * 64 + mf * 16 + lrow, kb);
        #pragma unroll
        for (int nf = 0; nf < 4; ++nf)
            bf[nf] = ldsfrag(bb, wn * 64 + nf * 16 + lrow, kb);

        __builtin_amdgcn_s_setprio(1);
        #pragma unroll
        for (int mf = 0; mf < 4; ++mf)
            #pragma unroll
            for (int nf = 0; nf < 4; ++nf)
                acc[mf][nf] = __builtin_amdgcn_mfma_f32_16x16x32_bf16(
                    af[mf], bf[nf], acc[mf][nf], 0, 0, 0);
        __builtin_amdgcn_s_setprio(0);

        __builtin_amdgcn_s_barrier();
        __builtin_amdgcn_sched_barrier(0);
    }

    const int sel = col0 >> 10;
    __bf16* outp = (sel == 0) ? o0 : (sel == 1) ? o1 : (sel == 2) ? o2 : o3;
    const int cb0 = col0 & 1023;

    if (sel <= 1) {
        const bool isQ = (sel == 0);
        const int lcol = ln & 15;
        // h is constant per thread: cb0 + wn*64 is 64-aligned, nf*16+lcol <= 63
        const int h = (cb0 + wn * 64) >> 6;
        const float l2g = __log2f(1.0f - exp2f(-5.0f - (float)h));
        const float sgn = isQ ? 1.0f : -1.0f;
        const float dstep   = exp2f(sgn * l2g);
        const float dstep16 = exp2f(sgn * 16.0f * l2g);

        const int r0b = row0 + wm * 64 + (ln >> 4) * 4;  // mf=0, reg=0 row
        const int s0b = r0b & (S - 1);
        const int sl0 = s0b & 63;

        // decay table for the 16 rows (offsets 16*mf + reg), shared by all nf
        float wdv[16];
        {
            float wdm = exp2f((isQ ? (float)(sl0 + 1)
                                   : (float)(63 - sl0)) * l2g);
            #pragma unroll
            for (int mf = 0; mf < 4; ++mf) {
                float wd = wdm;
                #pragma unroll
                for (int reg = 0; reg < 4; ++reg) {
                    wdv[mf * 4 + reg] = wd;
                    wd *= dstep;
                }
                wdm *= dstep16;
            }
        }

        #pragma unroll
        for (int nf = 0; nf < 4; ++nf) {
            const int cl = cb0 + wn * 64 + nf * 16 + lcol;
            const float bs = bias[col0 + wn * 64 + nf * 16 + lcol];
            const int d0 = nf * 16 + lcol;
            const bool rot = (d0 < 32);      // nf 0,1 rotate; 2,3 pass through
            if (rot) {
                const int j = d0 >> 1;
                const bool isEven = ((d0 & 1) == 0);
                const float invf = exp2f(-0.830482024f * (float)j);
                float l2base = __log2f(((float)(2 * j) + 12.8f) * (1.0f / 44.8f));
                if (!isQ) l2base = -l2base;
                const float cd  = __cosf(invf),          sd  = __sinf(invf);
                const float cd16 = __cosf(16.0f * invf), sd16 = __sinf(16.0f * invf);
                const float scstep   = exp2f(l2base * (1.0f / 512.0f));
                const float scstep16 = exp2f(l2base * (16.0f / 512.0f));
                const float th0 = (float)s0b * invf;
                float ccM = __cosf(th0), snM = __sinf(th0);
                float scM = exp2f(l2base * ((float)s0b - 1024.0f) * (1.0f / 512.0f));
                #pragma unroll
                for (int mf = 0; mf < 4; ++mf) {
                    float cc = ccM, sn = snM, sc = scM;
                    #pragma unroll
                    for (int reg = 0; reg < 4; ++reg) {
                        float v = acc[mf][nf][reg] + bs;
                        const float partner = __shfl_xor(v, 1, 64);
                        v = isEven ? (v * cc - partner * sn)
                                   : (v * cc + partner * sn);
                        v *= sc * wdv[mf * 4 + reg];
                        const int r = r0b + mf * 16 + reg;
                        outp[(size_t)r * 1024 + cl] = f2bf(v);
                        const float cn = cc * cd - sn * sd;
                        sn = sn * cd + cc * sd;
                        cc = cn;
                        sc *= scstep;
                    }
                    const float cM = ccM * cd16 - snM * sd16;
                    snM = snM * cd16 + ccM * sd16;
                    ccM = cM;
                    scM *= scstep16;
                }
            } else {
                #pragma unroll
                for (int mf = 0; mf < 4; ++mf) {
                    #pragma unroll
                    for (int reg = 0; reg < 4; ++reg) {
                        const float v = (acc[mf][nf][reg] + bs)
                                        * wdv[mf * 4 + reg];
                        const int r = r0b + mf * 16 + reg;
                        outp[(size_t)r * 1024 + cl] = f2bf(v);
                    }
                }
            }
        }
    } else {
        #pragma unroll
        for (int mf = 0; mf < 4; ++mf) {
            #pragma unroll
            for (int nf = 0; nf < 4; ++nf) {
                const int cl = cb0 + wn * 64 + nf * 16 + (ln & 15);
                const float bs = bias[col0 + wn * 64 + nf * 16 + (ln & 15)];
                #pragma unroll
                for (int reg = 0; reg < 4; ++reg) {
                    const int r = row0 + wm * 64 + mf * 16 + (ln >> 4) * 4 + reg;
                    outp[(size_t)r * 1024 + cl] = f2bf(acc[mf][nf][reg] + bs);
                }
            }
        }
    }
}

// ---------------------------------------------------------------------------
// Wo GEMM: 128x64 tile, 256 thr (4 waves 2x2, wave = 64r x 32c), ring-4
// 48KB LDS -> 2 blocks/CU, counted vmcnt(6/3/0), f32 out. Grid (16,32)=512.
// ---------------------------------------------------------------------------
__global__ __launch_bounds__(256) void gemm_wo_kernel(
    const __bf16* __restrict__ A, const __bf16* __restrict__ Bt,
    const float* __restrict__ bias, float* __restrict__ fout)
{
    __shared__ char lds[49152];     // A ring 4x8KB @0, B ring 4x4KB @32768
    constexpr int NTK = 32;

    const int tid = threadIdx.x, wv = tid >> 6, ln = tid & 63;
    const int row0 = blockIdx.y * 128, col0 = blockIdx.x * 64;
    const int wr = (wv >> 1) * 64, wc = (wv & 1) * 32;
    const int lrow = ln & 15, kb = (ln >> 4) * 16;

    f32x4 acc[4][2] = {};

    auto stageA = [&](int k0, char* buf) {
        #pragma unroll
        for (int j = 0; j < 2; ++j) {
            const int r  = j * 64 + (tid >> 2);
            const int cb = ((tid & 3) * 16) ^ (((r >> 1) & 3) << 4);
            GLOAD16((const char*)(A + ((size_t)(row0 + r) << 10) + k0) + cb,
                    buf + j * 4096 + wv * 1024);
        }
    };
    auto stageB = [&](int k0, char* buf) {
        const int r  = tid >> 2;
        const int cb = ((tid & 3) * 16) ^ (((r >> 1) & 3) << 4);
        GLOAD16((const char*)(Bt + ((size_t)(col0 + r) << 10) + k0) + cb,
                buf + wv * 1024);
    };

    #pragma unroll
    for (int tt = 0; tt < 3; ++tt) {
        stageA(tt * 32, lds + tt * 8192);
        stageB(tt * 32, lds + 32768 + tt * 4096);
    }
    asm volatile("s_waitcnt vmcnt(6)" ::: "memory");
    __builtin_amdgcn_s_barrier();
    __builtin_amdgcn_sched_barrier(0);

    for (int t = 0; t < NTK; ++t) {
        const char* ab = lds + (t & 3) * 8192;
        const char* bb = lds + 32768 + (t & 3) * 4096;
        bf16x8 af[4], bf[2];
        #pragma unroll
        for (int mi = 0; mi < 4; ++mi)
            af[mi] = ldsfrag(ab, wr + mi * 16 + lrow, kb);
        #pragma unroll
        for (int ni = 0; ni < 2; ++ni)
            bf[ni] = ldsfrag(bb, wc + ni * 16 + lrow, kb);

        if (t + 3 < NTK) {
            stageA((t + 3) * 32, lds + ((t + 3) & 3) * 8192);
            stageB((t + 3) * 32, lds + 32768 + ((t + 3) & 3) * 4096);
        }

        __builtin_amdgcn_s_setprio(1);
        #pragma unroll
        for (int mi = 0; mi < 4; ++mi)
            #pragma unroll
            for (int ni = 0; ni < 2; ++ni)
                acc[mi][ni] = __builtin_amdgcn_mfma_f32_16x16x32_bf16(
                    af[mi], bf[ni], acc[mi][ni], 0, 0, 0);
        __builtin_amdgcn_s_setprio(0);

        if (t <= NTK - 4)
            asm volatile("s_waitcnt vmcnt(6)" ::: "memory");
        else if (t == NTK - 3)
            asm volatile("s_waitcnt vmcnt(3)" ::: "memory");
        else if (t == NTK - 2)
            asm volatile("s_waitcnt vmcnt(0)" ::: "memory");
        __builtin_amdgcn_s_barrier();
        __builtin_amdgcn_sched_barrier(0);
    }

    #pragma unroll
    for (int mi = 0; mi < 4; ++mi) {
        #pragma unroll
        for (int ni = 0; ni < 2; ++ni) {
            const int c = col0 + wc + ni * 16 + (ln & 15);
            const float bs = bias[c];
            #pragma unroll
            for (int reg = 0; reg < 4; ++reg) {
                const int r = row0 + wr + mi * 16 + (ln >> 4) * 4 + reg;
                fout[(size_t)r * DMODEL + c] = acc[mi][ni][reg] + bs;
            }
        }
    }
}

// ---------------------------------------------------------------------------
// chunk_prep: per (chunk c, h, b): load K-hat,V 64x64 row-major; transpose in
// LDS; write V^T to global; compute U^T[dv][dk] = V^T @ K-hat via MFMA.
// ---------------------------------------------------------------------------
__global__ __launch_bounds__(256) void chunk_prep_kernel(
    const __bf16* __restrict__ kg, const __bf16* __restrict__ vg,
    __bf16* __restrict__ vt, float* __restrict__ U)
{
    __shared__ __bf16 ktile[64][72];
    __shared__ __bf16 vtile[64][72];
    __shared__ __bf16 ktl[64 * 64];    // transposed, swizzled
    __shared__ __bf16 vtl[64 * 64];

    const int c = blockIdx.x, h = blockIdx.y, b = blockIdx.z;
    const int bh = b * 16 + h;
    const int t = threadIdx.x, wv = t >> 6, ln = t & 63;
    const int lrow = ln & 15, lk8 = (ln >> 4) * 8;
    const size_t rowbase = ((size_t)b * S + c * 64) * DMODEL + h * 64;

    #pragma unroll
    for (int p = 0; p < 2; ++p) {
        const int ci = p * 256 + t;
        const int r = ci >> 3, c8 = (ci & 7) * 8;
        *reinterpret_cast<bf16x8*>(&ktile[r][c8]) =
            *reinterpret_cast<const bf16x8*>(&kg[rowbase + (size_t)r * DMODEL + c8]);
        *reinterpret_cast<bf16x8*>(&vtile[r][c8]) =
            *reinterpret_cast<const bf16x8*>(&vg[rowbase + (size_t)r * DMODEL + c8]);
    }
    __syncthreads();

    #pragma unroll
    for (int p = 0; p < 2; ++p) {
        const int ci = p * 256 + t;
        const int d = ci >> 3, s8 = (ci & 7) * 8;
        bf16x8 ok, ov;
        #pragma unroll
        for (int w = 0; w < 8; ++w) {
            ok[w] = ktile[s8 + w][d];
            ov[w] = vtile[s8 + w][d];
        }
        *reinterpret_cast<bf16x8*>(
            &vt[((size_t)bh * 64 + d) * 2048 + c * 64 + s8]) = ov;
        const int off = d * 128 + ((s8 * 2) ^ ((d & 7) << 4));
        *(bf16x8*)((char*)ktl + off) = ok;
        *(bf16x8*)((char*)vtl + off) = ov;
    }
    __syncthreads();

    f32x4 uacc[4] = {};
    #pragma unroll
    for (int ks = 0; ks < 2; ++ks) {
        const int arow = wv * 16 + lrow;
        const bf16x8 af = *(const bf16x8*)((char*)vtl + arow * 128 +
            (((ks * 32 + lk8) * 2) ^ ((arow & 7) << 4)));
        #pragma unroll
        for (int nf = 0; nf < 4; ++nf) {
            const int brow = nf * 16 + lrow;
            const bf16x8 bf_ = *(const bf16x8*)((char*)ktl + brow * 128 +
                (((ks * 32 + lk8) * 2) ^ ((brow & 7) << 4)));
            uacc[nf] = __builtin_amdgcn_mfma_f32_16x16x32_bf16(
                af, bf_, uacc[nf], 0, 0, 0);
        }
    }

    const size_t ub = ((size_t)bh * 32 + c) * 4096;
    #pragma unroll
    for (int nf = 0; nf < 4; ++nf) {
        const int dk = nf * 16 + (ln & 15);
        #pragma unroll
        for (int reg = 0; reg < 4; ++reg) {
            const int dv = wv * 16 + (ln >> 4) * 4 + reg;
            U[ub + dv * 64 + dk] = uacc[nf][reg];
        }
    }
}

// ---------------------------------------------------------------------------
// k2: scan S_c = gamma^64 * S_{c-1} + U_{c-1}. One (dv,dk) cell per thread,
// grid (16,32) = 512 blocks for TLP; 1-deep U prefetch hides L2 latency.
// ---------------------------------------------------------------------------
__global__ __launch_bounds__(256) void chunk_scan_kernel(
    const float* __restrict__ U, __bf16* __restrict__ St)
{
    const int bh = blockIdx.y;
    const int h = bh & 15;
    const float gamma = 1.0f - exp2f(-5.0f - (float)h);
    const float g64 = exp2f(64.0f * __log2f(gamma));
    const int t = threadIdx.x;
    const int dv = blockIdx.x * 4 + (t >> 6);
    const int dk = t & 63;
    const size_t ub = (size_t)bh * 32 * 4096 + (size_t)dv * 64 + dk;

    float s = 0.0f;
    float un = U[ub];                   // c = 0 prefetch
    for (int c = 0; c < 32; ++c) {
        const size_t sb = ub + (size_t)c * 4096;
        St[sb] = f2bf(s);
        const float uc = un;
        if (c < 31) un = U[sb + 4096];  // prefetch c+1 (independent of chain)
        s = g64 * s + uc;
    }
}

// ---------------------------------------------------------------------------
// k3: per-chunk retention + fused GN partial stats; ret stored as bf16.
// ---------------------------------------------------------------------------
__global__ __launch_bounds__(256) void retention_chunk_kernel(
    const __bf16* __restrict__ qg, const __bf16* __restrict__ kg,
    const __bf16* __restrict__ vt, const __bf16* __restrict__ St,
    __bf16* __restrict__ retb, float* __restrict__ part)
{
    __shared__ __bf16 qh[64 * 64];
    __shared__ __bf16 kh[64 * 64];
    __shared__ __bf16 vl[64 * 64];
    __shared__ __bf16 sl[64 * 64];
    __shared__ __bf16 pl[64 * 64];
    __shared__ float rs[4], rq[4];

    const int c = blockIdx.x, h = blockIdx.y, b = blockIdx.z;
    const int bh = b * 16 + h;
    const int t = threadIdx.x, wv = t >> 6, ln = t & 63;
    const int lrow = ln & 15, lk8 = (ln >> 4) * 8;

    const float gamma = 1.0f - exp2f(-5.0f - (float)h);
    const float l2g   = log2f(gamma);
    const float gm64i = exp2f(-64.0f * l2g);
    const size_t rowbase = ((size_t)b * S + c * 64) * DMODEL + h * 64;
    const size_t vtb = (size_t)bh * 64 * 2048 + c * 64;
    const size_t stb = ((size_t)bh * 32 + c) * 4096;

    #pragma unroll
    for (int p = 0; p < 2; ++p) {
        const int ci = p * 256 + t;
        const int r = ci >> 3, c8 = (ci & 7) * 8;
        const int off = r * 128 + ((c8 * 2) ^ ((r & 7) << 4));
        *(bf16x8*)((char*)qh + off) =
            *reinterpret_cast<const bf16x8*>(&qg[rowbase + (size_t)r * DMODEL + c8]);
        *(bf16x8*)((char*)kh + off) =
            *reinterpret_cast<const bf16x8*>(&kg[rowbase + (size_t)r * DMODEL + c8]);
        *(bf16x8*)((char*)vl + off) =
            *reinterpret_cast<const bf16x8*>(&vt[vtb + (size_t)r * 2048 + c8]);
        *(bf16x8*)((char*)sl + off) =
            *reinterpret_cast<const bf16x8*>(&St[stb + r * 64 + c8]);
    }
    __syncthreads();

    f32x4 sacc[4] = {};
    #pragma unroll
    for (int ks = 0; ks < 2; ++ks) {
        const int qrow = wv * 16 + lrow;
        const bf16x8 qf = *(const bf16x8*)((char*)qh + qrow * 128 +
            (((ks * 32 + lk8) * 2) ^ ((qrow & 7) << 4)));
        #pragma unroll
        for (int mi = 0; mi < 4; ++mi) {
            const int krow = mi * 16 + lrow;
            const bf16x8 kf = *(const bf16x8*)((char*)kh + krow * 128 +
                (((ks * 32 + lk8) * 2) ^ ((krow & 7) << 4)));
            sacc[mi] = __builtin_amdgcn_mfma_f32_16x16x32_bf16(
                kf, qf, sacc[mi], 0, 0, 0);
        }
    }

    const int iw = wv * 16 + (ln & 15);
    #pragma unroll
    for (int mi = 0; mi < 4; ++mi) {
        ushort4 pk;
        unsigned short* pkp = (unsigned short*)&pk;
        #pragma unroll
        for (int reg = 0; reg < 4; ++reg) {
            const int j = mi * 16 + (ln >> 4) * 4 + reg;
            const float pv = (j <= iw) ? sacc[mi][reg] * gm64i : 0.0f;
            const __bf16 pb = f2bf(pv);
            pkp[reg] = *(const unsigned short*)&pb;
        }
        const int jb8 = mi * 16 + (ln >> 4) * 4;
        *(ushort4*)((char*)pl + iw * 128 + ((jb8 * 2) ^ ((iw & 7) << 4))) = pk;
    }

    f32x4 acc[4] = {};
    #pragma unroll
    for (int ks = 0; ks < 2; ++ks) {
        const int prow = wv * 16 + lrow;
        const bf16x8 pf = *(const bf16x8*)((char*)pl + prow * 128 +
            (((ks * 32 + lk8) * 2) ^ ((prow & 7) << 4)));
        const bf16x8 qf2 = *(const bf16x8*)((char*)qh + prow * 128 +
            (((ks * 32 + lk8) * 2) ^ ((prow & 7) << 4)));
        #pragma unroll
        for (int nd = 0; nd < 4; ++nd) {
            const int vrow = nd * 16 + lrow;
            const bf16x8 vf = *(const bf16x8*)((char*)vl + vrow * 128 +
                (((ks * 32 + lk8) * 2) ^ ((vrow & 7) << 4)));
            const bf16x8 sf = *(const bf16x8*)((char*)sl + vrow * 128 +
                (((ks * 32 + lk8) * 2) ^ ((vrow & 7) << 4)));
            acc[nd] = __builtin_amdgcn_mfma_f32_16x16x32_bf16(
                pf, vf, acc[nd], 0, 0, 0);
            acc[nd] = __builtin_amdgcn_mfma_f32_16x16x32_bf16(
                qf2, sf, acc[nd], 0, 0, 0);
        }
    }

    const float sc5h = exp2f(5.0f + (float)h);
    float psum = 0.0f, psq = 0.0f;
    #pragma unroll
    for (int reg = 0; reg < 4; ++reg) {
        const int i = c * 64 + wv * 16 + (ln >> 4) * 4 + reg;
        const float omg = 1.0f - exp2f((float)(i + 1) * l2g);
        const float invn = rsqrtf(omg * sc5h);
        #pragma unroll
        for (int nd = 0; nd < 4; ++nd) {
            const float v = acc[nd][reg] * invn;
            retb[((size_t)b * S + i) * DMODEL + h * 64 + nd * 16 + (ln & 15)] =
                f2bf(v);
            psum += v;
            psq  += v * v;
        }
    }
    #pragma unroll
    for (int o = 32; o > 0; o >>= 1) {
        psum += __shfl_down(psum, o, 64);
        psq  += __shfl_down(psq, o, 64);
    }
    if (ln == 0) { rs[wv] = psum; rq[wv] = psq; }
    __syncthreads();
    if (t == 0) {
        part[((size_t)bh * 32 + c) * 2 + 0] = rs[0] + rs[1] + rs[2] + rs[3];
        part[((size_t)bh * 32 + c) * 2 + 1] = rq[0] + rq[1] + rq[2] + rq[3];
    }
}

// ---------------------------------------------------------------------------
// GN finalize + apply, fused: each block reduces its 16 heads' 32 chunk
// partials (part is 8KB, L2-resident), then applies GN * silu(gate).
// ---------------------------------------------------------------------------
__global__ __launch_bounds__(256) void gn_apply_kernel(
    const __bf16* __restrict__ retb, const __bf16* __restrict__ g,
    __bf16* __restrict__ y, const float* __restrict__ part,
    const float* __restrict__ gnw, const float* __restrict__ gnb)
{
    __shared__ float smean[16], srw[16];
    const int tid = threadIdx.x;
    const size_t p = (size_t)blockIdx.x * 256 + tid;  // group of 8
    const size_t el = p * 8;
    const int b = (int)(el >> 21);                    // uniform per block

    // in-block stats reduce: thread t -> head t>>4, chunks {t&15, (t&15)+16}
    {
        const int hh = tid >> 4, sub = tid & 15;
        const int bhh = b * H + hh;
        float s  = part[((size_t)bhh * 32 + sub) * 2 + 0]
                 + part[((size_t)bhh * 32 + sub + 16) * 2 + 0];
        float q2 = part[((size_t)bhh * 32 + sub) * 2 + 1]
                 + part[((size_t)bhh * 32 + sub + 16) * 2 + 1];
        #pragma unroll
        for (int o = 8; o > 0; o >>= 1) {
            s  += __shfl_down(s, o, 16);
            q2 += __shfl_down(q2, o, 16);
        }
        if (sub == 0) {
            const float inv_n = 1.0f / (float)(S * 64);
            const float mean = s * inv_n;
            const float var  = q2 * inv_n - mean * mean;
            smean[hh] = mean;
            srw[hh]   = rsqrtf(var + 1e-5f);
        }
    }
    __syncthreads();

    const int col = (int)(el & (DMODEL - 1));
    const int h   = col >> 6;
    const float mean = smean[h];
    const float w    = srw[h] * gnw[h];
    const float bb   = gnb[h];

    const bf16x8 rv = reinterpret_cast<const bf16x8*>(retb)[p];
    const bf16x8 gv = reinterpret_cast<const bf16x8*>(g)[p];
    bf16x8 o;
    #pragma unroll
    for (int i = 0; i < 8; ++i)
        o[i] = f2bf(((bf2f(rv[i]) - mean) * w + bb) * silu(bf2f(gv[i])));
    reinterpret_cast<bf16x8*>(y)[p] = o;
}

// ---------------------------------------------------------------------------
extern "C" void kernel_launch(void* const* d_in, const int* in_sizes, int n_in,
                              void* d_out, int out_size, void* d_ws, size_t ws_size,
                              hipStream_t stream)
{
    const float* x   = (const float*)d_in[0];
    const float* Wq  = (const float*)d_in[1];
    const float* bq  = (const float*)d_in[2];
    const float* Wk  = (const float*)d_in[3];
    const float* bk  = (const float*)d_in[4];
    const float* Wv  = (const float*)d_in[5];
    const float* bv  = (const float*)d_in[6];
    const float* Wg  = (const float*)d_in[7];
    const float* bg  = (const float*)d_in[8];
    const float* Wo  = (const float*)d_in[9];
    const float* bo  = (const float*)d_in[10];
    const float* gnw = (const float*)d_in[11];
    const float* gnb = (const float*)d_in[12];
    float* out = (float*)d_out;

    // workspace layout
    char* w = (char*)d_ws;
    __bf16* xb      = (__bf16*)w;               w += MAT * 2;            // 8.4MB
    __bf16* wqkvg_t = (__bf16*)w;               w += MAT * 2;            // 8.4MB
    __bf16* wo_t    = (__bf16*)w;               w += (size_t)DMODEL * DMODEL * 2;
    float*  bqkvg   = (float*)w;                w += 4096 * 4;
    __bf16* qb      = (__bf16*)w;               w += MAT * 2;
    __bf16* kb      = (__bf16*)w;               w += MAT * 2;
    __bf16* vb      = (__bf16*)w;               w += MAT * 2;
    __bf16* gb      = (__bf16*)w;               w += MAT * 2;
    __bf16* retb    = (__bf16*)w;               w += MAT * 2;            // bf16
    __bf16* yb      = (__bf16*)w;               w += MAT * 2;
    float*  U       = (float*)w;                w += MAT * 4;            // 16.8MB
    float*  part    = (float*)w;                w += 2048 * 4;
    // aliases over dead buffers:
    __bf16* vt = xb;               // xb dead after QKVG GEMM
    __bf16* St = (__bf16*)wqkvg_t; // wqkvg_t dead after QKVG GEMM (8.4MB)

    // 1) prep (merged cvt_x + transpose_w + pack_bias)
    prep_kernel<<<7184, 256, 0, stream>>>(x, xb, Wq, Wk, Wv, Wg, Wo,
                                          wqkvg_t, wo_t, bq, bk, bv, bg, bqkvg);

    // 2) fused QKVG projection GEMM + hoisted rotary/decay epilogue
    gemm_qkvg<<<512, 512, 0, stream>>>(xb, wqkvg_t, bqkvg, qb, kb, vb, gb);

    // 3) chunked retention: prep (transpose V + outer product) -> scan -> k3
    {
        dim3 grid(32, 16, 2);
        chunk_prep_kernel<<<grid, 256, 0, stream>>>(kb, vb, vt, U);
    }
    {
        dim3 grid(16, 32);
        chunk_scan_kernel<<<grid, 256, 0, stream>>>(U, St);
    }
    {
        dim3 grid(32, 16, 2);
        retention_chunk_kernel<<<grid, 256, 0, stream>>>(qb, kb, vt, St,
                                                         retb, part);
    }

    // 4) group norm finalize + apply with silu gate (stats fused in-block)
    gn_apply_kernel<<<2048, 256, 0, stream>>>(retb, gb, yb, part, gnw, gnb);

    // 5) output GEMM (4096 x 1024 x 1024), f32 out, 2 blocks/CU
    {
        dim3 grid(16, 32);
        gemm_wo_kernel<<<grid, 256, 0, stream>>>(yb, wo_t, bo, out);
    }
}

// Round 16
// 102.240 us; speedup vs baseline: 1.0717x; 1.0045x over previous
//
#include <hip/hip_runtime.h>
#include <math.h>

constexpr int B = 2;
constexpr int S = 2048;
constexpr int DMODEL = 1024;
constexpr int H = 16;
constexpr int M_TOT = B * S;                     // 4096
constexpr size_t MAT = (size_t)B * S * DMODEL;   // 4,194,304 elements

typedef __attribute__((ext_vector_type(8))) __bf16 bf16x8;
typedef __attribute__((ext_vector_type(4))) float f32x4;

#define GLOAD16(g, l) __builtin_amdgcn_global_load_lds( \
    (const __attribute__((address_space(1))) void*)(g), \
    (__attribute__((address_space(3))) void*)(l), 16, 0, 0)

__device__ __forceinline__ float bf2f(__bf16 v) { return (float)v; }
__device__ __forceinline__ __bf16 f2bf(float v) { return (__bf16)v; }
__device__ __forceinline__ float silu(float z) { return z / (1.0f + expf(-z)); }

// ---------------------------------------------------------------------------
// Merged prep: [0,2048) x fp32->bf16 ; [2048,7168) W transpose+convert ;
// [7168,7184) bias pack.
// ---------------------------------------------------------------------------
__global__ __launch_bounds__(256) void prep_kernel(
    const float* __restrict__ x, __bf16* __restrict__ xb,
    const float* Wq, const float* Wk, const float* Wv, const float* Wg,
    const float* Wo, __bf16* __restrict__ wqkvg_t, __bf16* __restrict__ wo_t,
    const float* bq, const float* bk, const float* bv, const float* bg,
    float* __restrict__ bqkvg)
{
    __shared__ float tile[32][33];
    const int bid = blockIdx.x;
    const int tid = threadIdx.x;

    if (bid < 2048) {
        const size_t p = (size_t)bid * 256 + tid;
        const float4 a = reinterpret_cast<const float4*>(x)[2 * p];
        const float4 b = reinterpret_cast<const float4*>(x)[2 * p + 1];
        bf16x8 o;
        o[0] = f2bf(a.x); o[1] = f2bf(a.y); o[2] = f2bf(a.z); o[3] = f2bf(a.w);
        o[4] = f2bf(b.x); o[5] = f2bf(b.y); o[6] = f2bf(b.z); o[7] = f2bf(b.w);
        reinterpret_cast<bf16x8*>(xb)[p] = o;
    } else if (bid < 7168) {
        const int idx = bid - 2048;
        const int z = idx >> 10;
        const int rem = idx & 1023;
        const int n0 = (rem & 31) * 32, k0 = (rem >> 5) * 32;
        const float* W = (z == 0) ? Wq : (z == 1) ? Wk : (z == 2) ? Wv
                        : (z == 3) ? Wg : Wo;
        const int tx = tid & 31, ty = tid >> 5;
        #pragma unroll
        for (int i = 0; i < 32; i += 8)
            tile[ty + i][tx] = W[(size_t)(k0 + ty + i) * DMODEL + n0 + tx];
        __syncthreads();
        #pragma unroll
        for (int i = 0; i < 32; i += 8) {
            const int n = n0 + ty + i, kk = k0 + tx;
            const __bf16 val = f2bf(tile[tx][ty + i]);
            if (z < 4) wqkvg_t[((size_t)z * 1024 + n) * DMODEL + kk] = val;
            else       wo_t[(size_t)n * DMODEL + kk] = val;
        }
    } else {
        const int i = (bid - 7168) * 256 + tid;
        const float* src = ((i >> 10) == 0) ? bq : ((i >> 10) == 1) ? bk
                          : ((i >> 10) == 2) ? bv : bg;
        bqkvg[i] = src[i & 1023];
    }
}

// ---------------------------------------------------------------------------
// Swizzled LDS layout for 64B (BK=32 bf16) rows.
// Physical slot = logical slot ^ ((row>>1)&3)  -> 2 lanes/bank (free).
// ---------------------------------------------------------------------------
__device__ __forceinline__ bf16x8 ldsfrag(const char* base, int row, int kbyte)
{
    return *(const bf16x8*)(base + row * 64 + (kbyte ^ (((row >> 1) & 3) << 4)));
}

// ---------------------------------------------------------------------------
// QKVG GEMM: 256x128 tile, 512 thr, ring-3 LDS 72KB, 2 blocks/CU, ONE barrier
// per K-tile (wo-kernel pattern, proven 8 rounds): ds_read frags(t) ->
// stage(t+2) -> MFMA -> counted vmcnt(3) -> barrier. Epilogue fuses xPos
// rotary + decay fold for q/k with fully hoisted transcendentals.
// ---------------------------------------------------------------------------
__global__ __launch_bounds__(512, 4) void gemm_qkvg(
    const __bf16* __restrict__ A, const __bf16* __restrict__ Bt,
    const float* __restrict__ bias,
    __bf16* o0, __bf16* o1, __bf16* o2, __bf16* o3)
{
    __shared__ char lds[73728];     // A ring 3x16KB @0, B ring 3x8KB @49152
    constexpr int NTK = 32;         // 1024 / 32

    const int tid = threadIdx.x, wv = tid >> 6, ln = tid & 63;
    const int wm = wv >> 1, wn = wv & 1;

    // bijective XCD swizzle (nwg=512, cpx=64)
    int bid = blockIdx.x;
    bid = (bid & 7) * 64 + (bid >> 3);
    const int bx = bid & 31, by = bid >> 5;
    const int row0 = by * 256, col0 = bx * 128;

    const int lrow = ln & 15;
    const int kb   = (ln >> 4) * 16;

    f32x4 acc[4][4] = {};

    auto stageA = [&](int k0, char* buf) {
        #pragma unroll
        for (int j = 0; j < 2; ++j) {
            const int r  = j * 128 + (tid >> 2);
            const int cb = ((tid & 3) * 16) ^ (((r >> 1) & 3) << 4);
            GLOAD16((const char*)(A + ((size_t)(row0 + r) << 10) + k0) + cb,
                    buf + j * 8192 + wv * 1024);
        }
    };
    auto stageB = [&](int k0, char* buf) {
        const int r  = tid >> 2;
        const int cb = ((tid & 3) * 16) ^ (((r >> 1) & 3) << 4);
        GLOAD16((const char*)(Bt + ((size_t)(col0 + r) << 10) + k0) + cb,
                buf + wv * 1024);
    };

    // prologue: stage tiles 0 and 1
    stageA(0, lds);
    stageB(0, lds + 49152);
    stageA(32, lds + 16384);
    stageB(32, lds + 49152 + 8192);
    asm volatile("s_waitcnt vmcnt(3)" ::: "memory");   // tile 0 landed
    __builtin_amdgcn_s_barrier();
    __builtin_amdgcn_sched_barrier(0);

    int slot = 0;                    // t % 3
    for (int t = 0; t < NTK; ++t) {
        const char* ab = lds + slot * 16384;
        const char* bb = lds + 49152 + slot * 8192;

        bf16x8 af[4], bf[4];
        #pragma unroll
        for (int mf = 0; mf < 4; ++mf)
            af[mf] = ldsfrag(ab, wm * 64 + mf * 16 + lrow, kb);
        #pragma unroll
        for (int nf = 0; nf < 4; ++nf)
            bf[nf] = ldsfrag(bb, wn * 64 + nf * 16 + lrow, kb);

        // stage tile t+2 into slot (t+2)%3 = (slot+2)%3 (its readers finished
        // before the end-of-(t-1) barrier)
        if (t + 2 < NTK) {
            const int s2 = (slot + 2 >= 3) ? slot - 1 : slot + 2;
            stageA((t + 2) * 32, lds + s2 * 16384);
            stageB((t + 2) * 32, lds + 49152 + s2 * 8192);
        }

        __builtin_amdgcn_s_setprio(1);
        #pragma unroll
        for (int mf = 0; mf < 4; ++mf)
            #pragma unroll
            for (int nf = 0; nf < 4; ++nf)
                acc[mf][nf] = __builtin_amdgcn_mfma_f32_16x16x32_bf16(
                    af[mf], bf[nf], acc[mf][nf], 0, 0, 0);
        __builtin_amdgcn_s_setprio(0);

        // publish tile t+1 (counted; drains only in the tail)
        if (t + 2 < NTK)
            asm volatile("s_waitcnt vmcnt(3)" ::: "memory");
        else if (t + 1 < NTK)
            asm volatile("s_waitcnt vmcnt(0)" ::: "memory");
        __builtin_amdgcn_s_barrier();
        __builtin_amdgcn_sched_barrier(0);

        slot = (slot + 1 >= 3) ? 0 : slot + 1;
    }

    const int sel = col0 >> 10;
    __bf16* outp = (sel == 0) ? o0 : (sel == 1) ? o1 : (sel == 2) ? o2 : o3;
    const int cb0 = col0 & 1023;

    if (sel <= 1) {
        const bool isQ = (sel == 0);
        const int lcol = ln & 15;
        // h is constant per thread: cb0 + wn*64 is 64-aligned, nf*16+lcol <= 63
        const int h = (cb0 + wn * 64) >> 6;
        const float l2g = __log2f(1.0f - exp2f(-5.0f - (float)h));
        const float sgn = isQ ? 1.0f : -1.0f;
        const float dstep   = exp2f(sgn * l2g);
        const float dstep16 = exp2f(sgn * 16.0f * l2g);

        const int r0b = row0 + wm * 64 + (ln >> 4) * 4;  // mf=0, reg=0 row
        const int s0b = r0b & (S - 1);
        const int sl0 = s0b & 63;

        // decay table for the 16 rows (offsets 16*mf + reg), shared by all nf
        float wdv[16];
        {
            float wdm = exp2f((isQ ? (float)(sl0 + 1)
                                   : (float)(63 - sl0)) * l2g);
            #pragma unroll
            for (int mf = 0; mf < 4; ++mf) {
                float wd = wdm;
                #pragma unroll
                for (int reg = 0; reg < 4; ++reg) {
                    wdv[mf * 4 + reg] = wd;
                    wd *= dstep;
                }
                wdm *= dstep16;
            }
        }

        #pragma unroll
        for (int nf = 0; nf < 4; ++nf) {
            const int cl = cb0 + wn * 64 + nf * 16 + lcol;
            const float bs = bias[col0 + wn * 64 + nf * 16 + lcol];
            const int d0 = nf * 16 + lcol;
            const bool rot = (d0 < 32);      // nf 0,1 rotate; 2,3 pass through
            if (rot) {
                const int j = d0 >> 1;
                const bool isEven = ((d0 & 1) == 0);
                const float invf = exp2f(-0.830482024f * (float)j);
                float l2base = __log2f(((float)(2 * j) + 12.8f) * (1.0f / 44.8f));
                if (!isQ) l2base = -l2base;
                const float cd  = __cosf(invf),          sd  = __sinf(invf);
                const float cd16 = __cosf(16.0f * invf), sd16 = __sinf(16.0f * invf);
                const float scstep   = exp2f(l2base * (1.0f / 512.0f));
                const float scstep16 = exp2f(l2base * (16.0f / 512.0f));
                const float th0 = (float)s0b * invf;
                float ccM = __cosf(th0), snM = __sinf(th0);
                float scM = exp2f(l2base * ((float)s0b - 1024.0f) * (1.0f / 512.0f));
                #pragma unroll
                for (int mf = 0; mf < 4; ++mf) {
                    float cc = ccM, sn = snM, sc = scM;
                    #pragma unroll
                    for (int reg = 0; reg < 4; ++reg) {
                        float v = acc[mf][nf][reg] + bs;
                        const float partner = __shfl_xor(v, 1, 64);
                        v = isEven ? (v * cc - partner * sn)
                                   : (v * cc + partner * sn);
                        v *= sc * wdv[mf * 4 + reg];
                        const int r = r0b + mf * 16 + reg;
                        outp[(size_t)r * 1024 + cl] = f2bf(v);
                        const float cn = cc * cd - sn * sd;
                        sn = sn * cd + cc * sd;
                        cc = cn;
                        sc *= scstep;
                    }
                    const float cM = ccM * cd16 - snM * sd16;
                    snM = snM * cd16 + ccM * sd16;
                    ccM = cM;
                    scM *= scstep16;
                }
            } else {
                #pragma unroll
                for (int mf = 0; mf < 4; ++mf) {
                    #pragma unroll
                    for (int reg = 0; reg < 4; ++reg) {
                        const float v = (acc[mf][nf][reg] + bs)
                                        * wdv[mf * 4 + reg];
                        const int r = r0b + mf * 16 + reg;
                        outp[(size_t)r * 1024 + cl] = f2bf(v);
                    }
                }
            }
        }
    } else {
        #pragma unroll
        for (int mf = 0; mf < 4; ++mf) {
            #pragma unroll
            for (int nf = 0; nf < 4; ++nf) {
                const int cl = cb0 + wn * 64 + nf * 16 + (ln & 15);
                const float bs = bias[col0 + wn * 64 + nf * 16 + (ln & 15)];
                #pragma unroll
                for (int reg = 0; reg < 4; ++reg) {
                    const int r = row0 + wm * 64 + mf * 16 + (ln >> 4) * 4 + reg;
                    outp[(size_t)r * 1024 + cl] = f2bf(acc[mf][nf][reg] + bs);
                }
            }
        }
    }
}

// ---------------------------------------------------------------------------
// Wo GEMM: 128x64 tile, 256 thr (4 waves 2x2, wave = 64r x 32c), ring-4
// 48KB LDS -> 2 blocks/CU, counted vmcnt(6/3/0), f32 out. Grid (16,32)=512.
// ---------------------------------------------------------------------------
__global__ __launch_bounds__(256) void gemm_wo_kernel(
    const __bf16* __restrict__ A, const __bf16* __restrict__ Bt,
    const float* __restrict__ bias, float* __restrict__ fout)
{
    __shared__ char lds[49152];     // A ring 4x8KB @0, B ring 4x4KB @32768
    constexpr int NTK = 32;

    const int tid = threadIdx.x, wv = tid >> 6, ln = tid & 63;
    const int row0 = blockIdx.y * 128, col0 = blockIdx.x * 64;
    const int wr = (wv >> 1) * 64, wc = (wv & 1) * 32;
    const int lrow = ln & 15, kb = (ln >> 4) * 16;

    f32x4 acc[4][2] = {};

    auto stageA = [&](int k0, char* buf) {
        #pragma unroll
        for (int j = 0; j < 2; ++j) {
            const int r  = j * 64 + (tid >> 2);
            const int cb = ((tid & 3) * 16) ^ (((r >> 1) & 3) << 4);
            GLOAD16((const char*)(A + ((size_t)(row0 + r) << 10) + k0) + cb,
                    buf + j * 4096 + wv * 1024);
        }
    };
    auto stageB = [&](int k0, char* buf) {
        const int r  = tid >> 2;
        const int cb = ((tid & 3) * 16) ^ (((r >> 1) & 3) << 4);
        GLOAD16((const char*)(Bt + ((size_t)(col0 + r) << 10) + k0) + cb,
                buf + wv * 1024);
    };

    #pragma unroll
    for (int tt = 0; tt < 3; ++tt) {
        stageA(tt * 32, lds + tt * 8192);
        stageB(tt * 32, lds + 32768 + tt * 4096);
    }
    asm volatile("s_waitcnt vmcnt(6)" ::: "memory");
    __builtin_amdgcn_s_barrier();
    __builtin_amdgcn_sched_barrier(0);

    for (int t = 0; t < NTK; ++t) {
        const char* ab = lds + (t & 3) * 8192;
        const char* bb = lds + 32768 + (t & 3) * 4096;
        bf16x8 af[4], bf[2];
        #pragma unroll
        for (int mi = 0; mi < 4; ++mi)
            af[mi] = ldsfrag(ab, wr + mi * 16 + lrow, kb);
        #pragma unroll
        for (int ni = 0; ni < 2; ++ni)
            bf[ni] = ldsfrag(bb, wc + ni * 16 + lrow, kb);

        if (t + 3 < NTK) {
            stageA((t + 3) * 32, lds + ((t + 3) & 3) * 8192);
            stageB((t + 3) * 32, lds + 32768 + ((t + 3) & 3) * 4096);
        }

        __builtin_amdgcn_s_setprio(1);
        #pragma unroll
        for (int mi = 0; mi < 4; ++mi)
            #pragma unroll
            for (int ni = 0; ni < 2; ++ni)
                acc[mi][ni] = __builtin_amdgcn_mfma_f32_16x16x32_bf16(
                    af[mi], bf[ni], acc[mi][ni], 0, 0, 0);
        __builtin_amdgcn_s_setprio(0);

        if (t <= NTK - 4)
            asm volatile("s_waitcnt vmcnt(6)" ::: "memory");
        else if (t == NTK - 3)
            asm volatile("s_waitcnt vmcnt(3)" ::: "memory");
        else if (t == NTK - 2)
            asm volatile("s_waitcnt vmcnt(0)" ::: "memory");
        __builtin_amdgcn_s_barrier();
        __builtin_amdgcn_sched_barrier(0);
    }

    #pragma unroll
    for (int mi = 0; mi < 4; ++mi) {
        #pragma unroll
        for (int ni = 0; ni < 2; ++ni) {
            const int c = col0 + wc + ni * 16 + (ln & 15);
            const float bs = bias[c];
            #pragma unroll
            for (int reg = 0; reg < 4; ++reg) {
                const int r = row0 + wr + mi * 16 + (ln >> 4) * 4 + reg;
                fout[(size_t)r * DMODEL + c] = acc[mi][ni][reg] + bs;
            }
        }
    }
}

// ---------------------------------------------------------------------------
// chunk_prep: per (chunk c, h, b): load K-hat,V 64x64 row-major; transpose in
// LDS; write V^T to global; compute U^T[dv][dk] = V^T @ K-hat via MFMA.
// ---------------------------------------------------------------------------
__global__ __launch_bounds__(256) void chunk_prep_kernel(
    const __bf16* __restrict__ kg, const __bf16* __restrict__ vg,
    __bf16* __restrict__ vt, float* __restrict__ U)
{
    __shared__ __bf16 ktile[64][72];
    __shared__ __bf16 vtile[64][72];
    __shared__ __bf16 ktl[64 * 64];    // transposed, swizzled
    __shared__ __bf16 vtl[64 * 64];

    const int c = blockIdx.x, h = blockIdx.y, b = blockIdx.z;
    const int bh = b * 16 + h;
    const int t = threadIdx.x, wv = t >> 6, ln = t & 63;
    const int lrow = ln & 15, lk8 = (ln >> 4) * 8;
    const size_t rowbase = ((size_t)b * S + c * 64) * DMODEL + h * 64;

    #pragma unroll
    for (int p = 0; p < 2; ++p) {
        const int ci = p * 256 + t;
        const int r = ci >> 3, c8 = (ci & 7) * 8;
        *reinterpret_cast<bf16x8*>(&ktile[r][c8]) =
            *reinterpret_cast<const bf16x8*>(&kg[rowbase + (size_t)r * DMODEL + c8]);
        *reinterpret_cast<bf16x8*>(&vtile[r][c8]) =
            *reinterpret_cast<const bf16x8*>(&vg[rowbase + (size_t)r * DMODEL + c8]);
    }
    __syncthreads();

    #pragma unroll
    for (int p = 0; p < 2; ++p) {
        const int ci = p * 256 + t;
        const int d = ci >> 3, s8 = (ci & 7) * 8;
        bf16x8 ok, ov;
        #pragma unroll
        for (int w = 0; w < 8; ++w) {
            ok[w] = ktile[s8 + w][d];
            ov[w] = vtile[s8 + w][d];
        }
        *reinterpret_cast<bf16x8*>(
            &vt[((size_t)bh * 64 + d) * 2048 + c * 64 + s8]) = ov;
        const int off = d * 128 + ((s8 * 2) ^ ((d & 7) << 4));
        *(bf16x8*)((char*)ktl + off) = ok;
        *(bf16x8*)((char*)vtl + off) = ov;
    }
    __syncthreads();

    f32x4 uacc[4] = {};
    #pragma unroll
    for (int ks = 0; ks < 2; ++ks) {
        const int arow = wv * 16 + lrow;
        const bf16x8 af = *(const bf16x8*)((char*)vtl + arow * 128 +
            (((ks * 32 + lk8) * 2) ^ ((arow & 7) << 4)));
        #pragma unroll
        for (int nf = 0; nf < 4; ++nf) {
            const int brow = nf * 16 + lrow;
            const bf16x8 bf_ = *(const bf16x8*)((char*)ktl + brow * 128 +
                (((ks * 32 + lk8) * 2) ^ ((brow & 7) << 4)));
            uacc[nf] = __builtin_amdgcn_mfma_f32_16x16x32_bf16(
                af, bf_, uacc[nf], 0, 0, 0);
        }
    }

    const size_t ub = ((size_t)bh * 32 + c) * 4096;
    #pragma unroll
    for (int nf = 0; nf < 4; ++nf) {
        const int dk = nf * 16 + (ln & 15);
        #pragma unroll
        for (int reg = 0; reg < 4; ++reg) {
            const int dv = wv * 16 + (ln >> 4) * 4 + reg;
            U[ub + dv * 64 + dk] = uacc[nf][reg];
        }
    }
}

// ---------------------------------------------------------------------------
// k2: scan S_c = gamma^64 * S_{c-1} + U_{c-1}. One (dv,dk) cell per thread,
// grid (16,32) = 512 blocks for TLP; 1-deep U prefetch hides L2 latency.
// ---------------------------------------------------------------------------
__global__ __launch_bounds__(256) void chunk_scan_kernel(
    const float* __restrict__ U, __bf16* __restrict__ St)
{
    const int bh = blockIdx.y;
    const int h = bh & 15;
    const float gamma = 1.0f - exp2f(-5.0f - (float)h);
    const float g64 = exp2f(64.0f * __log2f(gamma));
    const int t = threadIdx.x;
    const int dv = blockIdx.x * 4 + (t >> 6);
    const int dk = t & 63;
    const size_t ub = (size_t)bh * 32 * 4096 + (size_t)dv * 64 + dk;

    float s = 0.0f;
    float un = U[ub];                   // c = 0 prefetch
    for (int c = 0; c < 32; ++c) {
        const size_t sb = ub + (size_t)c * 4096;
        St[sb] = f2bf(s);
        const float uc = un;
        if (c < 31) un = U[sb + 4096];  // prefetch c+1 (independent of chain)
        s = g64 * s + uc;
    }
}

// ---------------------------------------------------------------------------
// k3: per-chunk retention + fused GN partial stats; ret stored as bf16.
// ---------------------------------------------------------------------------
__global__ __launch_bounds__(256) void retention_chunk_kernel(
    const __bf16* __restrict__ qg, const __bf16* __restrict__ kg,
    const __bf16* __restrict__ vt, const __bf16* __restrict__ St,
    __bf16* __restrict__ retb, float* __restrict__ part)
{
    __shared__ __bf16 qh[64 * 64];
    __shared__ __bf16 kh[64 * 64];
    __shared__ __bf16 vl[64 * 64];
    __shared__ __bf16 sl[64 * 64];
    __shared__ __bf16 pl[64 * 64];
    __shared__ float rs[4], rq[4];

    const int c = blockIdx.x, h = blockIdx.y, b = blockIdx.z;
    const int bh = b * 16 + h;
    const int t = threadIdx.x, wv = t >> 6, ln = t & 63;
    const int lrow = ln & 15, lk8 = (ln >> 4) * 8;

    const float gamma = 1.0f - exp2f(-5.0f - (float)h);
    const float l2g   = log2f(gamma);
    const float gm64i = exp2f(-64.0f * l2g);
    const size_t rowbase = ((size_t)b * S + c * 64) * DMODEL + h * 64;
    const size_t vtb = (size_t)bh * 64 * 2048 + c * 64;
    const size_t stb = ((size_t)bh * 32 + c) * 4096;

    #pragma unroll
    for (int p = 0; p < 2; ++p) {
        const int ci = p * 256 + t;
        const int r = ci >> 3, c8 = (ci & 7) * 8;
        const int off = r * 128 + ((c8 * 2) ^ ((r & 7) << 4));
        *(bf16x8*)((char*)qh + off) =
            *reinterpret_cast<const bf16x8*>(&qg[rowbase + (size_t)r * DMODEL + c8]);
        *(bf16x8*)((char*)kh + off) =
            *reinterpret_cast<const bf16x8*>(&kg[rowbase + (size_t)r * DMODEL + c8]);
        *(bf16x8*)((char*)vl + off) =
            *reinterpret_cast<const bf16x8*>(&vt[vtb + (size_t)r * 2048 + c8]);
        *(bf16x8*)((char*)sl + off) =
            *reinterpret_cast<const bf16x8*>(&St[stb + r * 64 + c8]);
    }
    __syncthreads();

    f32x4 sacc[4] = {};
    #pragma unroll
    for (int ks = 0; ks < 2; ++ks) {
        const int qrow = wv * 16 + lrow;
        const bf16x8 qf = *(const bf16x8*)((char*)qh + qrow * 128 +
            (((ks * 32 + lk8) * 2) ^ ((qrow & 7) << 4)));
        #pragma unroll
        for (int mi = 0; mi < 4; ++mi) {
            const int krow = mi * 16 + lrow;
            const bf16x8 kf = *(const bf16x8*)((char*)kh + krow * 128 +
                (((ks * 32 + lk8) * 2) ^ ((krow & 7) << 4)));
            sacc[mi] = __builtin_amdgcn_mfma_f32_16x16x32_bf16(
                kf, qf, sacc[mi], 0, 0, 0);
        }
    }

    const int iw = wv * 16 + (ln & 15);
    #pragma unroll
    for (int mi = 0; mi < 4; ++mi) {
        ushort4 pk;
        unsigned short* pkp = (unsigned short*)&pk;
        #pragma unroll
        for (int reg = 0; reg < 4; ++reg) {
            const int j = mi * 16 + (ln >> 4) * 4 + reg;
            const float pv = (j <= iw) ? sacc[mi][reg] * gm64i : 0.0f;
            const __bf16 pb = f2bf(pv);
            pkp[reg] = *(const unsigned short*)&pb;
        }
        const int jb8 = mi * 16 + (ln >> 4) * 4;
        *(ushort4*)((char*)pl + iw * 128 + ((jb8 * 2) ^ ((iw & 7) << 4))) = pk;
    }

    f32x4 acc[4] = {};
    #pragma unroll
    for (int ks = 0; ks < 2; ++ks) {
        const int prow = wv * 16 + lrow;
        const bf16x8 pf = *(const bf16x8*)((char*)pl + prow * 128 +
            (((ks * 32 + lk8) * 2) ^ ((prow & 7) << 4)));
        const bf16x8 qf2 = *(const bf16x8*)((char*)qh + prow * 128 +
            (((ks * 32 + lk8) * 2) ^ ((prow & 7) << 4)));
        #pragma unroll
        for (int nd = 0; nd < 4; ++nd) {
            const int vrow = nd * 16 + lrow;
            const bf16x8 vf = *(const bf16x8*)((char*)vl + vrow * 128 +
                (((ks * 32 + lk8) * 2) ^ ((vrow & 7) << 4)));
            const bf16x8 sf = *(const bf16x8*)((char*)sl + vrow * 128 +
                (((ks * 32 + lk8) * 2) ^ ((vrow & 7) << 4)));
            acc[nd] = __builtin_amdgcn_mfma_f32_16x16x32_bf16(
                pf, vf, acc[nd], 0, 0, 0);
            acc[nd] = __builtin_amdgcn_mfma_f32_16x16x32_bf16(
                qf2, sf, acc[nd], 0, 0, 0);
        }
    }

    const float sc5h = exp2f(5.0f + (float)h);
    float psum = 0.0f, psq = 0.0f;
    #pragma unroll
    for (int reg = 0; reg < 4; ++reg) {
        const int i = c * 64 + wv * 16 + (ln >> 4) * 4 + reg;
        const float omg = 1.0f - exp2f((float)(i + 1) * l2g);
        const float invn = rsqrtf(omg * sc5h);
        #pragma unroll
        for (int nd = 0; nd < 4; ++nd) {
            const float v = acc[nd][reg] * invn;
            retb[((size_t)b * S + i) * DMODEL + h * 64 + nd * 16 + (ln & 15)] =
                f2bf(v);
            psum += v;
            psq  += v * v;
        }
    }
    #pragma unroll
    for (int o = 32; o > 0; o >>= 1) {
        psum += __shfl_down(psum, o, 64);
        psq  += __shfl_down(psq, o, 64);
    }
    if (ln == 0) { rs[wv] = psum; rq[wv] = psq; }
    __syncthreads();
    if (t == 0) {
        part[((size_t)bh * 32 + c) * 2 + 0] = rs[0] + rs[1] + rs[2] + rs[3];
        part[((size_t)bh * 32 + c) * 2 + 1] = rq[0] + rq[1] + rq[2] + rq[3];
    }
}

// ---------------------------------------------------------------------------
// GN finalize + apply, fused: each block reduces its 16 heads' 32 chunk
// partials (part is 8KB, L2-resident), then applies GN * silu(gate).
// ---------------------------------------------------------------------------
__global__ __launch_bounds__(256) void gn_apply_kernel(
    const __bf16* __restrict__ retb, const __bf16* __restrict__ g,
    __bf16* __restrict__ y, const float* __restrict__ part,
    const float* __restrict__ gnw, const float* __restrict__ gnb)
{
    __shared__ float smean[16], srw[16];
    const int tid = threadIdx.x;
    const size_t p = (size_t)blockIdx.x * 256 + tid;  // group of 8
    const size_t el = p * 8;
    const int b = (int)(el >> 21);                    // uniform per block

    // in-block stats reduce: thread t -> head t>>4, chunks {t&15, (t&15)+16}
    {
        const int hh = tid >> 4, sub = tid & 15;
        const int bhh = b * H + hh;
        float s  = part[((size_t)bhh * 32 + sub) * 2 + 0]
                 + part[((size_t)bhh * 32 + sub + 16) * 2 + 0];
        float q2 = part[((size_t)bhh * 32 + sub) * 2 + 1]
                 + part[((size_t)bhh * 32 + sub + 16) * 2 + 1];
        #pragma unroll
        for (int o = 8; o > 0; o >>= 1) {
            s  += __shfl_down(s, o, 16);
            q2 += __shfl_down(q2, o, 16);
        }
        if (sub == 0) {
            const float inv_n = 1.0f / (float)(S * 64);
            const float mean = s * inv_n;
            const float var  = q2 * inv_n - mean * mean;
            smean[hh] = mean;
            srw[hh]   = rsqrtf(var + 1e-5f);
        }
    }
    __syncthreads();

    const int col = (int)(el & (DMODEL - 1));
    const int h   = col >> 6;
    const float mean = smean[h];
    const float w    = srw[h] * gnw[h];
    const float bb   = gnb[h];

    const bf16x8 rv = reinterpret_cast<const bf16x8*>(retb)[p];
    const bf16x8 gv = reinterpret_cast<const bf16x8*>(g)[p];
    bf16x8 o;
    #pragma unroll
    for (int i = 0; i < 8; ++i)
        o[i] = f2bf(((bf2f(rv[i]) - mean) * w + bb) * silu(bf2f(gv[i])));
    reinterpret_cast<bf16x8*>(y)[p] = o;
}

// ---------------------------------------------------------------------------
extern "C" void kernel_launch(void* const* d_in, const int* in_sizes, int n_in,
                              void* d_out, int out_size, void* d_ws, size_t ws_size,
                              hipStream_t stream)
{
    const float* x   = (const float*)d_in[0];
    const float* Wq  = (const float*)d_in[1];
    const float* bq  = (const float*)d_in[2];
    const float* Wk  = (const float*)d_in[3];
    const float* bk  = (const float*)d_in[4];
    const float* Wv  = (const float*)d_in[5];
    const float* bv  = (const float*)d_in[6];
    const float* Wg  = (const float*)d_in[7];
    const float* bg  = (const float*)d_in[8];
    const float* Wo  = (const float*)d_in[9];
    const float* bo  = (const float*)d_in[10];
    const float* gnw = (const float*)d_in[11];
    const float* gnb = (const float*)d_in[12];
    float* out = (float*)d_out;

    // workspace layout
    char* w = (char*)d_ws;
    __bf16* xb      = (__bf16*)w;               w += MAT * 2;            // 8.4MB
    __bf16* wqkvg_t = (__bf16*)w;               w += MAT * 2;            // 8.4MB
    __bf16* wo_t    = (__bf16*)w;               w += (size_t)DMODEL * DMODEL * 2;
    float*  bqkvg   = (float*)w;                w += 4096 * 4;
    __bf16* qb      = (__bf16*)w;               w += MAT * 2;
    __bf16* kb      = (__bf16*)w;               w += MAT * 2;
    __bf16* vb      = (__bf16*)w;               w += MAT * 2;
    __bf16* gb      = (__bf16*)w;               w += MAT * 2;
    __bf16* retb    = (__bf16*)w;               w += MAT * 2;            // bf16
    __bf16* yb      = (__bf16*)w;               w += MAT * 2;
    float*  U       = (float*)w;                w += MAT * 4;            // 16.8MB
    float*  part    = (float*)w;                w += 2048 * 4;
    // aliases over dead buffers:
    __bf16* vt = xb;               // xb dead after QKVG GEMM
    __bf16* St = (__bf16*)wqkvg_t; // wqkvg_t dead after QKVG GEMM (8.4MB)

    // 1) prep (merged cvt_x + transpose_w + pack_bias)
    prep_kernel<<<7184, 256, 0, stream>>>(x, xb, Wq, Wk, Wv, Wg, Wo,
                                          wqkvg_t, wo_t, bq, bk, bv, bg, bqkvg);

    // 2) fused QKVG projection GEMM + hoisted rotary/decay epilogue
    gemm_qkvg<<<512, 512, 0, stream>>>(xb, wqkvg_t, bqkvg, qb, kb, vb, gb);

    // 3) chunked retention: prep (transpose V + outer product) -> scan -> k3
    {
        dim3 grid(32, 16, 2);
        chunk_prep_kernel<<<grid, 256, 0, stream>>>(kb, vb, vt, U);
    }
    {
        dim3 grid(16, 32);
        chunk_scan_kernel<<<grid, 256, 0, stream>>>(U, St);
    }
    {
        dim3 grid(32, 16, 2);
        retention_chunk_kernel<<<grid, 256, 0, stream>>>(qb, kb, vt, St,
                                                         retb, part);
    }

    // 4) group norm finalize + apply with silu gate (stats fused in-block)
    gn_apply_kernel<<<2048, 256, 0, stream>>>(retb, gb, yb, part, gnw, gnb);

    // 5) output GEMM (4096 x 1024 x 1024), f32 out, 2 blocks/CU
    {
        dim3 grid(16, 32);
        gemm_wo_kernel<<<grid, 256, 0, stream>>>(yb, wo_t, bo, out);
    }
}